// Round 14
// baseline (1566.913 us; speedup 1.0000x reference)
//
#include <hip/hip_runtime.h>

#define NPTS 2048
#define CUF 384

__device__ __forceinline__ float lrelu(float y){ return y>=0.f ? y : 0.2f*y; }

// async global->LDS, 16B per lane; LDS dest = wave-uniform base + lane*16
#define GLD16(g, l) __builtin_amdgcn_global_load_lds( \
    (const __attribute__((address_space(1))) void*)(g), \
    (__attribute__((address_space(3))) void*)(l), 16, 0, 0)

// ---------------- build X_dn (point-major f32 [8][2048][384]) ----------------
__global__ void k_build_xdn(const float* __restrict__ dense,
                            const float* __restrict__ sparse,
                            float* __restrict__ X){
  int b = blockIdx.y, ch = blockIdx.x;  // ch = stick 0..31 (64 points)
  int t = threadIdx.x;                  // 256
  __shared__ float tile[64*128];        // 32 KB
  for (int k=0;k<32;k++){
    int f = t + k*256;                  // f = c*64 + j, c<128
    int c = f>>6, j = f&63;
    tile[j*128 + c] = dense[((size_t)b*128 + c)*NPTS + ch*64 + j];
  }
  __syncthreads();
  for (int k=0;k<32;k++){
    int f = t + k*256;                  // f = j*128 + c
    int j = f>>7, c = f&127;
    X[((size_t)b*NPTS + ch*64 + j)*CUF + c] = tile[f];
  }
  float v = sparse[((size_t)b*256 + t)*32 + ch];
  for (int j=0;j<64;j++) X[((size_t)b*NPTS + ch*64 + j)*CUF + 128 + t] = v;
}

// ---------------- row sum-of-squares, numpy-pairwise mimic ----------------
__global__ void k_sn(const float* __restrict__ X, float* __restrict__ sn){
  int g = blockIdx.x*256 + threadIdx.x;   // 16384 = 8*2048 points
  if (g >= 8*NPTS) return;
  const float* row = X + (size_t)g*CUF;
  float blk[4];
  #pragma unroll
  for (int bI=0;bI<4;bI++){
    const float* p = row + bI*96;
    float r[8];
    #pragma unroll
    for (int l=0;l<8;l++) r[l] = __fmul_rn(p[l], p[l]);
    #pragma unroll 1
    for (int i=8;i<96;i+=8){
      #pragma unroll
      for (int l=0;l<8;l++) r[l] = __fadd_rn(r[l], __fmul_rn(p[i+l], p[i+l]));
    }
    float s01 = __fadd_rn(r[0], r[1]);
    float s23 = __fadd_rn(r[2], r[3]);
    float s45 = __fadd_rn(r[4], r[5]);
    float s67 = __fadd_rn(r[6], r[7]);
    blk[bI] = __fadd_rn(__fadd_rn(s01, s23), __fadd_rn(s45, s67));
  }
  sn[g] = __fadd_rn(__fadd_rn(blk[0], blk[1]), __fadd_rn(blk[2], blk[3]));
}

// ---------------- triangular dot tiles -> global Dot[bb][r][c] ----------------
// dot = ascending-c FMA chain (bit-exact symmetric). Block (rb,cb), cb>=rb:
// writes row region directly; off-diagonal also writes transposed region via LDS.
__global__ __launch_bounds__(256) void k_dist_tri(
    const float* __restrict__ X, float* __restrict__ Dot, int b_base){
  int z = blockIdx.z; int b = b_base + z;
  int t = threadIdx.x;
  int tx = t & 15, ty = t >> 4;
  int idx = blockIdx.x, rb = 0;
  while (idx >= 16 - rb){ idx -= 16 - rb; rb++; }
  int cb = rb + idx;
  __shared__ float U[8448];          // staging; Ds[128][65] aliases
  float* Xr = U;
  float* Xc = U + 4096;
  float* Ds = U;
  int r0 = rb*128;
  int c0 = cb*128;
  const size_t xb = (size_t)b*NPTS*CUF;
  const size_t zb = (size_t)z*NPTS*NPTS;

  int wv  = t >> 6;
  int sub = (t & 63) >> 3;
  int gs  = t & 7;
  int rowsA[4]; int swzA[4];
  #pragma unroll
  for (int cc=0;cc<4;cc++){
    int grp = wv*4 + cc;
    int row = grp*8 + sub;
    rowsA[cc] = row;
    swzA[cc] = 4*(gs ^ (row&7));
  }

  float acc[8][8];
  #pragma unroll
  for (int i=0;i<8;i++){
    #pragma unroll
    for (int j=0;j<8;j++) acc[i][j] = 0.f;
  }
  for (int kt=0; kt<12; kt++){
    int k0 = kt*32;
    __syncthreads();
    #pragma unroll
    for (int cc=0;cc<4;cc++){
      int grp = wv*4 + cc;
      GLD16(X + xb + (size_t)(r0+rowsA[cc])*CUF + k0 + swzA[cc], Xr + grp*256);
      GLD16(X + xb + (size_t)(c0+rowsA[cc])*CUF + k0 + swzA[cc], Xc + grp*256);
    }
    __syncthreads();
    #pragma unroll
    for (int kk=0; kk<32; kk+=4){
      int G = kk>>2;
      float4 aa[8], bb[8];
      #pragma unroll
      for (int i=0;i<8;i++){ int r = ty+16*i; aa[i] = *(const float4*)&Xr[r*32 + 4*(G ^ (r&7))]; }
      #pragma unroll
      for (int j=0;j<8;j++){ int r = tx+16*j; bb[j] = *(const float4*)&Xc[r*32 + 4*(G ^ (r&7))]; }
      #pragma unroll
      for (int i=0;i<8;i++){
        #pragma unroll
        for (int j=0;j<8;j++){
          float a_ = acc[i][j];
          a_ = fmaf(aa[i].x, bb[j].x, a_);
          a_ = fmaf(aa[i].y, bb[j].y, a_);
          a_ = fmaf(aa[i].z, bb[j].z, a_);
          a_ = fmaf(aa[i].w, bb[j].w, a_);
          acc[i][j] = a_;
        }
      }
    }
  }
  // row region
  #pragma unroll
  for (int i=0;i<8;i++){
    size_t rbase = zb + (size_t)(r0 + ty + 16*i)*NPTS + c0;
    #pragma unroll
    for (int j=0;j<8;j++) Dot[rbase + tx + 16*j] = acc[i][j];
  }
  // transposed region (off-diagonal)
  if (rb != cb){
    for (int h=0; h<2; h++){
      __syncthreads();
      #pragma unroll
      for (int i2=0;i2<4;i2++){
        #pragma unroll
        for (int j=0;j<8;j++){
          Ds[(tx+16*j)*65 + ty + 16*i2] = acc[h*4+i2][j];
        }
      }
      __syncthreads();
      for (int e=t; e<128*64; e+=256){
        int col = e>>6, rr = e&63;
        Dot[zb + (size_t)(c0+col)*NPTS + r0 + h*64 + rr] = Ds[col*65 + rr];
      }
    }
  }
}

// ---------------- whole-row top-10: one wave per row ----------------
// d = fl( fl(sn_r + sn_c) - fl(2*dot) ); lexicographic (val,idx) selection == top_k.
#define INS10(V, I) { \
  bool bet = ((V) < tv[9]) || ((V) == tv[9] && (I) < ti[9]); \
  if (bet){ tv[9]=(V); ti[9]=(I); \
    _Pragma("unroll") \
    for (int q=9;q>=1;q--){ \
      bool sw = (tv[q] < tv[q-1]) || (tv[q] == tv[q-1] && ti[q] < ti[q-1]); \
      float f0 = sw ? tv[q] : tv[q-1]; float f1 = sw ? tv[q-1] : tv[q]; \
      int   i0 = sw ? ti[q] : ti[q-1]; int   i1 = sw ? ti[q-1] : ti[q]; \
      tv[q-1]=f0; tv[q]=f1; ti[q-1]=i0; ti[q]=i1; \
    } \
  } }

__global__ __launch_bounds__(256) void k_sel(const float* __restrict__ Dot,
                                             const float* __restrict__ sn,
                                             int* __restrict__ idx, int b_base){
  int t = threadIdx.x;
  int lane = t & 63, w = t >> 6;
  int rglob = blockIdx.x*4 + w;          // 0..8191
  int bb = rglob >> 11;
  int r  = rglob & 2047;
  int b  = b_base + bb;
  const float* drow = Dot + ((size_t)bb*NPTS + r)*NPTS;
  const float* snp  = sn + (size_t)b*NPTS;
  float snr = snp[r];
  float tv[10]; int ti[10];
  #pragma unroll
  for (int q=0;q<10;q++){ tv[q] = 3.4e38f; ti[q] = 0x7fffffff; }
  int c0 = lane*32;
  #pragma unroll 1
  for (int c4=0;c4<32;c4+=4){
    float4 dd = *(const float4*)&drow[c0+c4];
    float4 ss = *(const float4*)&snp[c0+c4];
    float v0 = __fsub_rn(__fadd_rn(snr, ss.x), __fmul_rn(2.0f, dd.x));
    float v1 = __fsub_rn(__fadd_rn(snr, ss.y), __fmul_rn(2.0f, dd.y));
    float v2 = __fsub_rn(__fadd_rn(snr, ss.z), __fmul_rn(2.0f, dd.z));
    float v3 = __fsub_rn(__fadd_rn(snr, ss.w), __fmul_rn(2.0f, dd.w));
    INS10(v0, c0+c4+0);
    INS10(v1, c0+c4+1);
    INS10(v2, c0+c4+2);
    INS10(v3, c0+c4+3);
  }
  // 6 xor-merge levels: insert partner's sorted 10
  #pragma unroll
  for (int m=0;m<6;m++){
    int msk = 1<<m;
    float ov[10]; int oi[10];
    #pragma unroll
    for (int q=0;q<10;q++){ ov[q] = __shfl_xor(tv[q], msk, 64); oi[q] = __shfl_xor(ti[q], msk, 64); }
    #pragma unroll
    for (int q=0;q<10;q++){ INS10(ov[q], oi[q]); }
  }
  if (lane == 0){
    int* o = idx + ((size_t)b*NPTS + r)*10;
    #pragma unroll
    for (int q=0;q<10;q++) o[q] = ti[q];
  }
}

// ---------------- W -> [W1 ; W2-W1] ----------------
__global__ void k_prepw(const float* __restrict__ Wsrc, float* __restrict__ Wcat, int Ohalf){
  int g = blockIdx.x*256 + threadIdx.x;
  int total = Ohalf*2*CUF;
  if (g >= total) return;
  int o = g / CUF, c = g % CUF;
  float v;
  if (o < Ohalf) v = Wsrc[(size_t)o*768 + c];
  else { int oo = o - Ohalf; v = Wsrc[(size_t)oo*768 + 384 + c] - Wsrc[(size_t)oo*768 + c]; }
  Wcat[g] = v;
}

// ---------------- dense GEMM 128x128x(BK=32), gload_lds staging ----------------
__global__ __launch_bounds__(256) void k_gemm_pq2(const float* __restrict__ A, const float* __restrict__ W,
                         const float* __restrict__ bias, float* __restrict__ OUT){
  int b = blockIdx.z, mb = blockIdx.y, ob = blockIdx.x;   // (4,16,8)
  int t = threadIdx.x; int tx = t&15, ty = t>>4;
  __shared__ float Xa[4096];
  __shared__ float Xw[4096];
  int m0 = mb*128, o0 = ob*128;
  float acc[8][8];
  #pragma unroll
  for (int i=0;i<8;i++){
    #pragma unroll
    for (int j=0;j<8;j++) acc[i][j] = 0.f;
  }
  int wv  = t >> 6;
  int sub = (t & 63) >> 3;
  int gs  = t & 7;
  int rowsA[4]; int swzA[4];
  #pragma unroll
  for (int cc=0;cc<4;cc++){
    int grp = wv*4 + cc;
    int row = grp*8 + sub;
    rowsA[cc] = row;
    swzA[cc] = 4*(gs ^ (row&7));
  }
  for (int kt=0; kt<12; kt++){
    int k0 = kt*32;
    __syncthreads();
    #pragma unroll
    for (int cc=0;cc<4;cc++){
      int grp = wv*4 + cc;
      GLD16(A + ((size_t)b*NPTS + m0 + rowsA[cc])*CUF + k0 + swzA[cc], Xa + grp*256);
      GLD16(W + (size_t)(o0 + rowsA[cc])*CUF + k0 + swzA[cc], Xw + grp*256);
    }
    __syncthreads();
    #pragma unroll
    for (int kk=0; kk<32; kk+=4){
      int G = kk>>2;
      float4 aa[8], bb[8];
      #pragma unroll
      for (int i=0;i<8;i++){ int r = ty+16*i; aa[i] = *(const float4*)&Xa[r*32 + 4*(G ^ (r&7))]; }
      #pragma unroll
      for (int j=0;j<8;j++){ int r = tx+16*j; bb[j] = *(const float4*)&Xw[r*32 + 4*(G ^ (r&7))]; }
      #pragma unroll
      for (int i=0;i<8;i++){
        #pragma unroll
        for (int j=0;j<8;j++){
          float a_ = acc[i][j];
          a_ = fmaf(aa[i].x, bb[j].x, a_);
          a_ = fmaf(aa[i].y, bb[j].y, a_);
          a_ = fmaf(aa[i].z, bb[j].z, a_);
          a_ = fmaf(aa[i].w, bb[j].w, a_);
          acc[i][j] = a_;
        }
      }
    }
  }
  #pragma unroll
  for (int i=0;i<8;i++){
    int m = m0 + ty + 16*i;
    #pragma unroll
    for (int j=0;j<8;j++){
      int o = o0 + tx + 16*j;
      float v = acc[i][j];
      if (o >= 256) v += bias[o - 256];
      OUT[((size_t)b*NPTS + m)*512 + o] = v;
    }
  }
}

// ---------------- GEMM (small, for sparse path) ----------------
__global__ __launch_bounds__(256) void k_gemm_pq(const float* __restrict__ A, const float* __restrict__ W,
                         const float* __restrict__ bias,
                         float* __restrict__ OUT, int M, int Ototal, int Ohalf){
  int b = blockIdx.z, mb = blockIdx.y, ob = blockIdx.x;
  int t = threadIdx.x; int tr = t&15, tc = t>>4;
  __shared__ float At[64][68], Wt[64][68];
  int m0 = mb*64, o0 = ob*64;
  float acc[4][4];
  #pragma unroll
  for(int i=0;i<4;i++){
    #pragma unroll
    for(int j=0;j<4;j++) acc[i][j]=0.f;
  }
  int li = t>>2, lk = (t&3)*16;
  for (int kt=0;kt<6;kt++){
    int k0 = kt*64;
    {
      int m = m0 + li;
      if (m < M){
        const float4* p = (const float4*)(A + ((size_t)b*M + m)*CUF + k0 + lk);
        #pragma unroll
        for (int e=0;e<4;e++) *(float4*)&At[li][lk+e*4] = p[e];
      } else {
        float4 z = make_float4(0.f,0.f,0.f,0.f);
        #pragma unroll
        for (int e=0;e<4;e++) *(float4*)&At[li][lk+e*4] = z;
      }
      const float4* pw = (const float4*)(W + (size_t)(o0+li)*CUF + k0 + lk);
      #pragma unroll
      for (int e=0;e<4;e++) *(float4*)&Wt[li][lk+e*4] = pw[e];
    }
    __syncthreads();
    #pragma unroll
    for (int k4=0;k4<16;k4++){
      float4 aa[4], bb[4];
      aa[0] = *(const float4*)&At[tr   ][k4*4];
      aa[1] = *(const float4*)&At[tr+16][k4*4];
      aa[2] = *(const float4*)&At[tr+32][k4*4];
      aa[3] = *(const float4*)&At[tr+48][k4*4];
      bb[0] = *(const float4*)&Wt[tc   ][k4*4];
      bb[1] = *(const float4*)&Wt[tc+16][k4*4];
      bb[2] = *(const float4*)&Wt[tc+32][k4*4];
      bb[3] = *(const float4*)&Wt[tc+48][k4*4];
      #pragma unroll
      for(int i=0;i<4;i++){
        #pragma unroll
        for(int j=0;j<4;j++)
          acc[i][j] += aa[i].x*bb[j].x + aa[i].y*bb[j].y + aa[i].z*bb[j].z + aa[i].w*bb[j].w;
      }
    }
    __syncthreads();
  }
  #pragma unroll
  for(int i=0;i<4;i++){
    int m = m0 + tr + 16*i;
    if (m < M){
      #pragma unroll
      for(int j=0;j<4;j++){
        int o = o0 + tc + 16*j;
        float v = acc[i][j];
        if (o >= Ohalf) v += bias[o - Ohalf];
        OUT[((size_t)b*M + m)*Ototal + o] = v;
      }
    }
  }
}

// ---------------- dense GCN gather + stats + max/min ----------------
__global__ __launch_bounds__(256) void k_gather_dn(const float* __restrict__ PQ, const int* __restrict__ idx,
                            float* __restrict__ dmax, float* __restrict__ dmin, double* __restrict__ part){
  int b = blockIdx.y, nb = blockIdx.x; int t = threadIdx.x;
  __shared__ int sidx[640];
  int n0 = nb*64;
  for (int k=t; k<640; k+=256) sidx[k] = idx[((size_t)b*NPTS + n0)*10 + k] & 2047;
  __syncthreads();
  double s=0.0, s2=0.0;
  const size_t pb = (size_t)b*NPTS*512;
  for (int n=0;n<64;n++){
    float qv = PQ[pb + (size_t)(n0+n)*512 + 256 + t];
    float mx = -3.4e38f, mn = 3.4e38f;
    #pragma unroll
    for (int k=0;k<10;k++){
      int m = sidx[n*10+k];
      float h = PQ[pb + (size_t)m*512 + t] + qv;
      mx = fmaxf(mx,h); mn = fminf(mn,h);
      s += h; s2 += (double)h*(double)h;
    }
    dmax[((size_t)b*NPTS + n0+n)*256 + t] = mx;
    dmin[((size_t)b*NPTS + n0+n)*256 + t] = mn;
  }
  size_t blk = (size_t)b*32 + nb;
  part[(blk*256 + t)*2] = s; part[(blk*256 + t)*2+1] = s2;
}

// ---------------- generic channel stats reduce -> (mean, invstd) ----------------
__global__ void k_reduce(const double* __restrict__ part, float* __restrict__ mv,
                         int nblk, int C, int count){
  int c = blockIdx.x; int t = threadIdx.x;
  double s=0.0, s2=0.0;
  for (int k=t;k<nblk;k+=64){ s += part[((size_t)k*C+c)*2]; s2 += part[((size_t)k*C+c)*2+1]; }
  #pragma unroll
  for (int off=32; off>=1; off>>=1){ s += __shfl_down(s, off, 64); s2 += __shfl_down(s2, off, 64); }
  if (t==0){
    double mean = s / (double)count;
    double var = s2 / (double)count - mean*mean;
    mv[c*2] = (float)mean;
    mv[c*2+1] = (float)(1.0 / sqrt(var + 1e-5));
  }
}

// ---------------- BN+act epilogue choosing max/min by sign(gamma); in-place on xmax ----------------
__global__ void k_epi(const float* __restrict__ xmin, float* __restrict__ xmax,
                      const float* __restrict__ mv, const float* __restrict__ g,
                      const float* __restrict__ be, int C, size_t total){
  size_t i = (size_t)blockIdx.x*256 + threadIdx.x;
  if (i>=total) return;
  int c = (int)(i % (size_t)C);
  float gg = g[c];
  float x = gg >= 0.f ? xmax[i] : xmin[i];
  float y = gg*(x - mv[c*2])*mv[c*2+1] + be[c];
  xmax[i] = lrelu(y);
}

// ---------------- d2s conv(1x3 valid) + stats + per-(b,c,s) max/min ----------------
__global__ __launch_bounds__(128) void k_d2s(const float* __restrict__ dense,
                      const float* __restrict__ w, const float* __restrict__ bias,
                      float* __restrict__ mx, float* __restrict__ mn, double* __restrict__ part){
  int b = blockIdx.y, s = blockIdx.x; int t = threadIdx.x; // 128
  __shared__ float IN[128*64];
  for (int k=0;k<64;k++){
    int f = t + k*128;
    int ci = f>>6, wj = f&63;
    IN[f] = dense[((size_t)b*128 + ci)*NPTS + s*64 + wj];
  }
  __syncthreads();
  float acc[62];
  float bv = bias[t];
  #pragma unroll
  for (int wj=0;wj<62;wj++) acc[wj]=bv;
  for (int ci=0;ci<128;ci++){
    const float* wp = w + ((size_t)t*128 + ci)*3;
    float w0 = wp[0], w1 = wp[1], w2 = wp[2];
    const float* row = &IN[ci*64];
    #pragma unroll
    for (int wj=0;wj<62;wj++) acc[wj] += row[wj]*w0 + row[wj+1]*w1 + row[wj+2]*w2;
  }
  float vmx=-3.4e38f, vmn=3.4e38f; double ss=0.0, ss2=0.0;
  #pragma unroll
  for (int wj=0;wj<62;wj++){ float v = acc[wj]; vmx=fmaxf(vmx,v); vmn=fminf(vmn,v); ss+=v; ss2+=(double)v*(double)v; }
  mx[((size_t)b*32+s)*128 + t] = vmx;
  mn[((size_t)b*32+s)*128 + t] = vmn;
  part[(((size_t)b*32+s)*128 + t)*2] = ss; part[(((size_t)b*32+s)*128 + t)*2+1] = ss2;
}

// ---------------- build union_sparse points Xs f32 [8][32][384] ----------------
__global__ void k_build_xs(const float* __restrict__ sparse,
                           const float* __restrict__ mx, const float* __restrict__ mn,
                           const float* __restrict__ mv, const float* __restrict__ g,
                           const float* __restrict__ be, float* __restrict__ Xs){
  int b = blockIdx.x; int c = threadIdx.x; // 384
  for (int n=0;n<32;n++){
    float v;
    if (c < 256) v = sparse[((size_t)b*256 + c)*32 + n];
    else {
      int cc = c-256;
      float gg = g[cc];
      float x = gg>=0.f ? mx[((size_t)b*32+n)*128+cc] : mn[((size_t)b*32+n)*128+cc];
      v = lrelu(gg*(x - mv[cc*2])*mv[cc*2+1] + be[cc]);
    }
    Xs[((size_t)b*32+n)*384 + c] = v;
  }
}

// ---------------- sparse kNN (k=2 of 32) ----------------
__global__ __launch_bounds__(256) void k_knn_sp(const float* __restrict__ Xs, int* __restrict__ idx){
  int b = blockIdx.x; int t = threadIdx.x;
  __shared__ float Xh[32*388];
  __shared__ float snl[32];
  __shared__ float D[32*33];
  for (int k=t;k<32*384;k+=256){ int n=k/384, c=k-n*384; Xh[n*388+c] = Xs[(size_t)b*32*384 + k]; }
  __syncthreads();
  if (t<32){ double s=0.0; for (int c=0;c<384;c++){ double v=(double)Xh[t*388+c]; s+=v*v; } snl[t]=(float)s; }
  __syncthreads();
  for (int p=t;p<1024;p+=256){
    int n=p>>5, m=p&31;
    const float* A=&Xh[n*388]; const float* B=&Xh[m*388];
    double s=0.0;
    for (int c=0;c<384;c++) s += (double)A[c]*(double)B[c];
    D[n*33+m] = (float)((double)snl[m] - 2.0*s);
  }
  __syncthreads();
  if (t<32){
    float v0=3.4e38f,v1=3.4e38f; int i0=0,i1=0;
    for (int m=0;m<32;m++){
      float v=D[t*33+m];
      if (v < v0){ v1=v0;i1=i0; v0=v;i0=m; }
      else if (v < v1){ v1=v;i1=m; }
    }
    idx[((size_t)b*32+t)*2]=i0; idx[((size_t)b*32+t)*2+1]=i1;
  }
}

// ---------------- sparse GCN gather + stats + max/min ----------------
__global__ void k_gather_sp(const float* __restrict__ PQ, const int* __restrict__ idx,
                            float* __restrict__ umax, float* __restrict__ umin, double* __restrict__ part){
  int b = blockIdx.x; int t = threadIdx.x; // 512
  double s=0.0, s2=0.0;
  for (int n=0;n<32;n++){
    float qv = PQ[((size_t)b*32+n)*1024 + 512 + t];
    float mxv=-3.4e38f, mnv=3.4e38f;
    #pragma unroll
    for (int k=0;k<2;k++){
      int m = idx[((size_t)b*32+n)*2+k] & 31;
      float h = PQ[((size_t)b*32+m)*1024 + t] + qv;
      mxv=fmaxf(mxv,h); mnv=fminf(mnv,h); s+=h; s2+=(double)h*(double)h;
    }
    umax[((size_t)b*32+n)*512+t]=mxv; umin[((size_t)b*32+n)*512+t]=mnv;
  }
  part[((size_t)b*512+t)*2]=s; part[((size_t)b*512+t)*2+1]=s2;
}

// ---------------- FPS (16 of 32) ----------------
__global__ void k_fps(const float* __restrict__ coor, int* __restrict__ fps){
  int b = blockIdx.x; int t = threadIdx.x; // 64
  __shared__ float C[32*64]; __shared__ float dist[32]; __shared__ int fs;
  for (int k=t;k<2048;k+=64) C[k] = coor[(size_t)b*2048 + k];
  if (t<32) dist[t]=1e10f;
  if (t==0) fs=0;
  __syncthreads();
  for (int it=0; it<16; it++){
    int f = fs;
    if (t==0) fps[b*16+it] = f;
    if (t<32){
      float d=0.f;
      for (int c=0;c<64;c++){ float df = C[t*64+c]-C[f*64+c]; d += df*df; }
      dist[t] = fminf(dist[t], d);
    }
    __syncthreads();
    if (t==0){
      float bd=-1.f; int bi=0;
      for (int n=0;n<32;n++){ if (dist[n]>bd){bd=dist[n];bi=n;} }
      fs=bi;
    }
    __syncthreads();
  }
}

// ---------------- outputs 0 and 2 ----------------
__global__ void k_out0(const float* __restrict__ usp, const int* __restrict__ fps, float* __restrict__ out0){
  int b = blockIdx.y, s = blockIdx.x; int t = threadIdx.x; // 512
  int n = fps[b*16+s] & 31;
  out0[((size_t)b*512 + t)*16 + s] = usp[((size_t)b*32+n)*512 + t];
}
__global__ void k_out2(const float* __restrict__ coor, const int* __restrict__ fps, float* __restrict__ out2){
  int b = blockIdx.x; int t = threadIdx.x; // 256
  for (int e=t; e<1024; e+=256){
    int s=e>>6, c=e&63;
    out2[(size_t)b*1024 + e] = coor[((size_t)b*32 + (fps[b*16+s]&31))*64 + c];
  }
}

// ---------------- dcv conv (1x3, stride 2, pad 1) on gathered sticks; 2-pass over ci ----------------
__global__ __launch_bounds__(256) void k_dcv(const float* __restrict__ gdn, const int* __restrict__ fps,
                      const float* __restrict__ w, const float* __restrict__ bias,
                      float* __restrict__ pre, double* __restrict__ part){
  int b = blockIdx.y, s = blockIdx.x; int t = threadIdx.x; // 256
  __shared__ float I[64*128];  // 32 KB
  int n0 = (fps[b*16+s] & 31)*64;
  const size_t gbase = ((size_t)b*NPTS + n0)*256;
  float acc[32];
  float bv = bias[t];
  #pragma unroll
  for (int q=0;q<32;q++) acc[q]=bv;
  for (int half=0; half<2; half++){
    int cbase = half*128;
    __syncthreads();
    for (int e=t; e<8192; e+=256){
      int p = e>>7, c = e&127;
      I[e] = gdn[gbase + (size_t)p*256 + cbase + c];
    }
    __syncthreads();
    for (int ci=0; ci<128; ci+=4){
      float wv[4][3];
      const float* wp = w + ((size_t)t*256 + cbase + ci)*3;
      #pragma unroll
      for (int q=0;q<4;q++){ wv[q][0]=wp[q*3]; wv[q][1]=wp[q*3+1]; wv[q][2]=wp[q*3+2]; }
      #pragma unroll
      for (int q=0;q<32;q++){
        float4 ev = *(const float4*)&I[(2*q)*128 + ci];
        acc[q] += ev.x*wv[0][1] + ev.y*wv[1][1] + ev.z*wv[2][1] + ev.w*wv[3][1];
        float4 ov = *(const float4*)&I[(2*q+1)*128 + ci];
        acc[q] += ov.x*wv[0][2] + ov.y*wv[1][2] + ov.z*wv[2][2] + ov.w*wv[3][2];
        if (q < 31) acc[q+1] += ov.x*wv[0][0] + ov.y*wv[1][0] + ov.z*wv[2][0] + ov.w*wv[3][0];
      }
    }
  }
  double ss=0.0, ss2=0.0;
  #pragma unroll
  for (int q=0;q<32;q++){ ss += acc[q]; ss2 += (double)acc[q]*(double)acc[q]; }
  float* o = pre + (((size_t)b*256 + t)*16 + s)*32;
  #pragma unroll
  for (int q=0;q<32;q++) o[q] = acc[q];
  part[(((size_t)b*16+s)*256 + t)*2] = ss; part[(((size_t)b*16+s)*256 + t)*2+1] = ss2;
}

__global__ void k_epi_dcv(const float* __restrict__ pre, const float* __restrict__ mv,
                          const float* __restrict__ g, const float* __restrict__ be,
                          float* __restrict__ out1){
  size_t i = (size_t)blockIdx.x*256 + threadIdx.x; // 1,048,576
  int c = (int)((i>>9) & 255);
  float gg = g[c];
  float y = gg*(pre[i]-mv[c*2])*mv[c*2+1] + be[c];
  out1[i] = lrelu(y);
}

extern "C" void kernel_launch(void* const* d_in, const int* in_sizes, int n_in,
                              void* d_out, int out_size, void* d_ws, size_t ws_size,
                              hipStream_t stream){
  const float* sparse = (const float*)d_in[0];
  const float* dense  = (const float*)d_in[1];
  const float* coor   = (const float*)d_in[2];
  const float* d2s_w  = (const float*)d_in[3];
  const float* d2s_b  = (const float*)d_in[4];
  const float* d2s_g  = (const float*)d_in[5];
  const float* d2s_be = (const float*)d_in[6];
  const float* gsp_w  = (const float*)d_in[7];
  const float* gsp_b  = (const float*)d_in[8];
  const float* gsp_g  = (const float*)d_in[9];
  const float* gsp_be = (const float*)d_in[10];
  const float* gdn_w  = (const float*)d_in[11];
  const float* gdn_b  = (const float*)d_in[12];
  const float* gdn_g  = (const float*)d_in[13];
  const float* gdn_be = (const float*)d_in[14];
  const float* dcv_w  = (const float*)d_in[15];
  const float* dcv_b  = (const float*)d_in[16];
  const float* dcv_g  = (const float*)d_in[17];
  const float* dcv_be = (const float*)d_in[18];

  float* out0 = (float*)d_out;
  float* out1 = out0 + 8*512*16;
  float* out2 = out1 + (size_t)8*256*512;

  char* base = (char*)d_ws; size_t off = 0;
  auto alloc = [&](size_t bytes)->void*{ void* p = base + off; off += (bytes + 255) & ~(size_t)255; return p; };
  float* Xdn  = (float*)alloc((size_t)8*2048*384*4);
  float* sn   = (float*)alloc((size_t)8*2048*4);
  int*   idxd = (int*)alloc((size_t)8*2048*10*4);
  float* PQ   = (float*)alloc((size_t)8*2048*512*4);
  float* dmax = (float*)alloc((size_t)8*2048*256*4);
  float* dmin = (float*)alloc((size_t)8*2048*256*4);
  double* partdn = (double*)alloc((size_t)256*256*2*8);
  float* mvdn = (float*)alloc(256*2*4);
  float* Wcd  = (float*)alloc((size_t)512*384*4);
  float* Wcs  = (float*)alloc((size_t)1024*384*4);
  float* Xs   = (float*)alloc((size_t)8*32*384*4);
  int*   idxs = (int*)alloc(8*32*2*4);
  float* PQs  = (float*)alloc((size_t)8*32*1024*4);
  float* umax = (float*)alloc((size_t)8*32*512*4);
  float* umin = (float*)alloc((size_t)8*32*512*4);
  double* partsp = (double*)alloc((size_t)8*512*2*8);
  float* mvsp = (float*)alloc(512*2*4);
  float* d2mx = (float*)alloc((size_t)8*32*128*4);
  float* d2mn = (float*)alloc((size_t)8*32*128*4);
  double* partd2 = (double*)alloc((size_t)256*128*2*8);
  float* mvd2 = (float*)alloc(128*2*4);
  int* fps = (int*)alloc(8*16*4);
  float* dcvpre = (float*)alloc((size_t)8*256*512*4);
  double* partdcv = (double*)alloc((size_t)128*256*2*8);
  float* mvdcv = (float*)alloc(256*2*4);
  if (off > ws_size) return;  // diagnostic: output stays zero -> ws too small

  // Dot (4 batches x 2048 x 2048 f32 = 67.1 MB) overlays PQ..mvdcv (~73 MB):
  // everything in that region is written only AFTER k_sel consumed Dot.
  float* Dot = PQ;

  k_build_xdn<<<dim3(32,8), 256, 0, stream>>>(dense, sparse, Xdn);
  k_sn<<<64, 256, 0, stream>>>(Xdn, sn);
  k_dist_tri<<<dim3(136,1,4), 256, 0, stream>>>(Xdn, Dot, 0);
  k_sel<<<2048, 256, 0, stream>>>(Dot, sn, idxd, 0);
  k_dist_tri<<<dim3(136,1,4), 256, 0, stream>>>(Xdn, Dot, 4);
  k_sel<<<2048, 256, 0, stream>>>(Dot, sn, idxd, 4);
  k_prepw<<<768, 256, 0, stream>>>(gdn_w, Wcd, 256);
  k_prepw<<<1536, 256, 0, stream>>>(gsp_w, Wcs, 512);
  k_gemm_pq2<<<dim3(4,16,8), 256, 0, stream>>>(Xdn, Wcd, gdn_b, PQ);
  k_gather_dn<<<dim3(32,8), 256, 0, stream>>>(PQ, idxd, dmax, dmin, partdn);
  k_reduce<<<256, 64, 0, stream>>>(partdn, mvdn, 256, 256, 163840);
  k_epi<<<16384, 256, 0, stream>>>(dmin, dmax, mvdn, gdn_g, gdn_be, 256, (size_t)8*2048*256);
  k_d2s<<<dim3(32,8), 128, 0, stream>>>(dense, d2s_w, d2s_b, d2mx, d2mn, partd2);
  k_reduce<<<128, 64, 0, stream>>>(partd2, mvd2, 256, 128, 15872);
  k_build_xs<<<8, 384, 0, stream>>>(sparse, d2mx, d2mn, mvd2, d2s_g, d2s_be, Xs);
  k_knn_sp<<<8, 256, 0, stream>>>(Xs, idxs);
  k_gemm_pq<<<dim3(16,1,8), 256, 0, stream>>>(Xs, Wcs, gsp_b, PQs, 32, 1024, 512);
  k_gather_sp<<<8, 512, 0, stream>>>(PQs, idxs, umax, umin, partsp);
  k_reduce<<<512, 64, 0, stream>>>(partsp, mvsp, 8, 512, 512);
  k_epi<<<512, 256, 0, stream>>>(umin, umax, mvsp, gsp_g, gsp_be, 512, (size_t)8*32*512);
  k_fps<<<8, 64, 0, stream>>>(coor, fps);
  k_out0<<<dim3(16,8), 512, 0, stream>>>(umax, fps, out0);
  k_out2<<<8, 256, 0, stream>>>(coor, fps, out2);
  k_dcv<<<dim3(16,8), 256, 0, stream>>>(dmax, fps, dcv_w, dcv_b, dcvpre, partdcv);
  k_reduce<<<256, 64, 0, stream>>>(partdcv, mvdcv, 128, 256, 4096);
  k_epi_dcv<<<4096, 256, 0, stream>>>(dcvpre, mvdcv, dcv_g, dcv_be, out1);
}

// Round 15
// 835.843 us; speedup vs baseline: 1.8746x; 1.8746x over previous
//
#include <hip/hip_runtime.h>

#define NPTS 2048
#define CUF 384

__device__ __forceinline__ float lrelu(float y){ return y>=0.f ? y : 0.2f*y; }

// async global->LDS, 16B per lane; LDS dest = wave-uniform base + lane*16
#define GLD16(g, l) __builtin_amdgcn_global_load_lds( \
    (const __attribute__((address_space(1))) void*)(g), \
    (__attribute__((address_space(3))) void*)(l), 16, 0, 0)

// ---------------- build X_dn (point-major f32 [8][2048][384]) ----------------
__global__ void k_build_xdn(const float* __restrict__ dense,
                            const float* __restrict__ sparse,
                            float* __restrict__ X){
  int b = blockIdx.y, ch = blockIdx.x;  // ch = stick 0..31 (64 points)
  int t = threadIdx.x;                  // 256
  __shared__ float tile[64*128];        // 32 KB
  for (int k=0;k<32;k++){
    int f = t + k*256;                  // f = c*64 + j, c<128
    int c = f>>6, j = f&63;
    tile[j*128 + c] = dense[((size_t)b*128 + c)*NPTS + ch*64 + j];
  }
  __syncthreads();
  for (int k=0;k<32;k++){
    int f = t + k*256;                  // f = j*128 + c
    int j = f>>7, c = f&127;
    X[((size_t)b*NPTS + ch*64 + j)*CUF + c] = tile[f];
  }
  float v = sparse[((size_t)b*256 + t)*32 + ch];
  for (int j=0;j<64;j++) X[((size_t)b*NPTS + ch*64 + j)*CUF + 128 + t] = v;
}

// ---------------- row sum-of-squares, numpy-pairwise mimic ----------------
__global__ void k_sn(const float* __restrict__ X, float* __restrict__ sn){
  int g = blockIdx.x*256 + threadIdx.x;   // 16384 = 8*2048 points
  if (g >= 8*NPTS) return;
  const float* row = X + (size_t)g*CUF;
  float blk[4];
  #pragma unroll
  for (int bI=0;bI<4;bI++){
    const float* p = row + bI*96;
    float r[8];
    #pragma unroll
    for (int l=0;l<8;l++) r[l] = __fmul_rn(p[l], p[l]);
    #pragma unroll 1
    for (int i=8;i<96;i+=8){
      #pragma unroll
      for (int l=0;l<8;l++) r[l] = __fadd_rn(r[l], __fmul_rn(p[i+l], p[i+l]));
    }
    float s01 = __fadd_rn(r[0], r[1]);
    float s23 = __fadd_rn(r[2], r[3]);
    float s45 = __fadd_rn(r[4], r[5]);
    float s67 = __fadd_rn(r[6], r[7]);
    blk[bI] = __fadd_rn(__fadd_rn(s01, s23), __fadd_rn(s45, s67));
  }
  sn[g] = __fadd_rn(__fadd_rn(blk[0], blk[1]), __fadd_rn(blk[2], blk[3]));
}

// ---------------- triangular dot tiles -> global Dot[bb][r][c] ----------------
// dot = ascending-c FMA chain (bit-exact symmetric). Block (rb,cb), cb>=rb:
// writes row region directly; off-diagonal also writes transposed region via LDS.
__global__ __launch_bounds__(256) void k_dist_tri(
    const float* __restrict__ X, float* __restrict__ Dot, int b_base){
  int z = blockIdx.z; int b = b_base + z;
  int t = threadIdx.x;
  int tx = t & 15, ty = t >> 4;
  int idx = blockIdx.x, rb = 0;
  while (idx >= 16 - rb){ idx -= 16 - rb; rb++; }
  int cb = rb + idx;
  __shared__ float U[8448];          // staging; Ds[128][65] aliases
  float* Xr = U;
  float* Xc = U + 4096;
  float* Ds = U;
  int r0 = rb*128;
  int c0 = cb*128;
  const size_t xb = (size_t)b*NPTS*CUF;
  const size_t zb = (size_t)z*NPTS*NPTS;

  int wv  = t >> 6;
  int sub = (t & 63) >> 3;
  int gs  = t & 7;
  int rowsA[4]; int swzA[4];
  #pragma unroll
  for (int cc=0;cc<4;cc++){
    int grp = wv*4 + cc;
    int row = grp*8 + sub;
    rowsA[cc] = row;
    swzA[cc] = 4*(gs ^ (row&7));
  }

  float acc[8][8];
  #pragma unroll
  for (int i=0;i<8;i++){
    #pragma unroll
    for (int j=0;j<8;j++) acc[i][j] = 0.f;
  }
  for (int kt=0; kt<12; kt++){
    int k0 = kt*32;
    __syncthreads();
    #pragma unroll
    for (int cc=0;cc<4;cc++){
      int grp = wv*4 + cc;
      GLD16(X + xb + (size_t)(r0+rowsA[cc])*CUF + k0 + swzA[cc], Xr + grp*256);
      GLD16(X + xb + (size_t)(c0+rowsA[cc])*CUF + k0 + swzA[cc], Xc + grp*256);
    }
    __syncthreads();
    #pragma unroll
    for (int kk=0; kk<32; kk+=4){
      int G = kk>>2;
      float4 aa[8], bb[8];
      #pragma unroll
      for (int i=0;i<8;i++){ int r = ty+16*i; aa[i] = *(const float4*)&Xr[r*32 + 4*(G ^ (r&7))]; }
      #pragma unroll
      for (int j=0;j<8;j++){ int r = tx+16*j; bb[j] = *(const float4*)&Xc[r*32 + 4*(G ^ (r&7))]; }
      #pragma unroll
      for (int i=0;i<8;i++){
        #pragma unroll
        for (int j=0;j<8;j++){
          float a_ = acc[i][j];
          a_ = fmaf(aa[i].x, bb[j].x, a_);
          a_ = fmaf(aa[i].y, bb[j].y, a_);
          a_ = fmaf(aa[i].z, bb[j].z, a_);
          a_ = fmaf(aa[i].w, bb[j].w, a_);
          acc[i][j] = a_;
        }
      }
    }
  }
  // row region
  #pragma unroll
  for (int i=0;i<8;i++){
    size_t rbase = zb + (size_t)(r0 + ty + 16*i)*NPTS + c0;
    #pragma unroll
    for (int j=0;j<8;j++) Dot[rbase + tx + 16*j] = acc[i][j];
  }
  // transposed region (off-diagonal)
  if (rb != cb){
    for (int h=0; h<2; h++){
      __syncthreads();
      #pragma unroll
      for (int i2=0;i2<4;i2++){
        #pragma unroll
        for (int j=0;j<8;j++){
          Ds[(tx+16*j)*65 + ty + 16*i2] = acc[h*4+i2][j];
        }
      }
      __syncthreads();
      for (int e=t; e<128*64; e+=256){
        int col = e>>6, rr = e&63;
        Dot[zb + (size_t)(c0+col)*NPTS + r0 + h*64 + rr] = Ds[col*65 + rr];
      }
    }
  }
}

// ---------------- whole-row top-10: one wave per row, u64-key wave-min ----------------
// d = fl( fl(sn_r + sn_c) - fl(2*dot) ); key = (flip(d)<<32)|idx; u64 order ==
// lexicographic (d, idx) == top_k semantics. 10 rounds of filtered wave-min.
__global__ __launch_bounds__(256) void k_sel(const float* __restrict__ Dot,
                                             const float* __restrict__ sn,
                                             int* __restrict__ idx, int b_base){
  int t = threadIdx.x;
  int lane = t & 63, w = t >> 6;
  int rglob = blockIdx.x*4 + w;          // 0..8191
  int bb = rglob >> 11;
  int r  = rglob & 2047;
  int b  = b_base + bb;
  const float* drow = Dot + ((size_t)bb*NPTS + r)*NPTS;
  const float* snp  = sn + (size_t)b*NPTS;
  float snr = snp[r];
  unsigned long long key[32];
  #pragma unroll
  for (int k=0;k<8;k++){
    int cbase = k*256 + lane*4;          // coalesced: wave covers contiguous 1KB
    float4 dd = *(const float4*)&drow[cbase];
    float4 ss = *(const float4*)&snp[cbase];
    float v0 = __fsub_rn(__fadd_rn(snr, ss.x), __fmul_rn(2.0f, dd.x));
    float v1 = __fsub_rn(__fadd_rn(snr, ss.y), __fmul_rn(2.0f, dd.y));
    float v2 = __fsub_rn(__fadd_rn(snr, ss.z), __fmul_rn(2.0f, dd.z));
    float v3 = __fsub_rn(__fadd_rn(snr, ss.w), __fmul_rn(2.0f, dd.w));
    float vv[4] = {v0, v1, v2, v3};
    #pragma unroll
    for (int u=0;u<4;u++){
      unsigned int bits = __float_as_uint(vv[u]);
      unsigned int flip = bits ^ ((unsigned int)((int)bits >> 31) | 0x80000000u);
      key[k*4+u] = ((unsigned long long)flip << 32) | (unsigned int)(cbase + u);
    }
  }
  unsigned long long last = 0ull;
  int out[10];
  #pragma unroll
  for (int q=0;q<10;q++){
    const unsigned long long INF = 0xFFFFFFFFFFFFFFFFull;
    unsigned long long m0[16];
    #pragma unroll
    for (int s=0;s<16;s++){
      unsigned long long a = (key[s]    > last) ? key[s]    : INF;
      unsigned long long c = (key[s+16] > last) ? key[s+16] : INF;
      m0[s] = (c < a) ? c : a;
    }
    #pragma unroll
    for (int s=0;s<8;s++) m0[s] = (m0[s+8] < m0[s]) ? m0[s+8] : m0[s];
    #pragma unroll
    for (int s=0;s<4;s++) m0[s] = (m0[s+4] < m0[s]) ? m0[s+4] : m0[s];
    m0[0] = (m0[2] < m0[0]) ? m0[2] : m0[0];
    m0[1] = (m0[3] < m0[1]) ? m0[3] : m0[1];
    unsigned long long m = (m0[1] < m0[0]) ? m0[1] : m0[0];
    #pragma unroll
    for (int sh=1; sh<64; sh<<=1){
      unsigned long long o = (unsigned long long)__shfl_xor((long long)m, sh, 64);
      m = (o < m) ? o : m;
    }
    last = m;
    out[q] = (int)(m & 0xFFFFFFFFull);
  }
  if (lane == 0){
    int* o = idx + ((size_t)b*NPTS + r)*10;
    #pragma unroll
    for (int q=0;q<10;q++) o[q] = out[q];
  }
}

// ---------------- W -> [W1 ; W2-W1] ----------------
__global__ void k_prepw(const float* __restrict__ Wsrc, float* __restrict__ Wcat, int Ohalf){
  int g = blockIdx.x*256 + threadIdx.x;
  int total = Ohalf*2*CUF;
  if (g >= total) return;
  int o = g / CUF, c = g % CUF;
  float v;
  if (o < Ohalf) v = Wsrc[(size_t)o*768 + c];
  else { int oo = o - Ohalf; v = Wsrc[(size_t)oo*768 + 384 + c] - Wsrc[(size_t)oo*768 + c]; }
  Wcat[g] = v;
}

// ---------------- dense GEMM 128x128x(BK=32), gload_lds staging ----------------
__global__ __launch_bounds__(256) void k_gemm_pq2(const float* __restrict__ A, const float* __restrict__ W,
                         const float* __restrict__ bias, float* __restrict__ OUT){
  int b = blockIdx.z, mb = blockIdx.y, ob = blockIdx.x;   // (4,16,8)
  int t = threadIdx.x; int tx = t&15, ty = t>>4;
  __shared__ float Xa[4096];
  __shared__ float Xw[4096];
  int m0 = mb*128, o0 = ob*128;
  float acc[8][8];
  #pragma unroll
  for (int i=0;i<8;i++){
    #pragma unroll
    for (int j=0;j<8;j++) acc[i][j] = 0.f;
  }
  int wv  = t >> 6;
  int sub = (t & 63) >> 3;
  int gs  = t & 7;
  int rowsA[4]; int swzA[4];
  #pragma unroll
  for (int cc=0;cc<4;cc++){
    int grp = wv*4 + cc;
    int row = grp*8 + sub;
    rowsA[cc] = row;
    swzA[cc] = 4*(gs ^ (row&7));
  }
  for (int kt=0; kt<12; kt++){
    int k0 = kt*32;
    __syncthreads();
    #pragma unroll
    for (int cc=0;cc<4;cc++){
      int grp = wv*4 + cc;
      GLD16(A + ((size_t)b*NPTS + m0 + rowsA[cc])*CUF + k0 + swzA[cc], Xa + grp*256);
      GLD16(W + (size_t)(o0 + rowsA[cc])*CUF + k0 + swzA[cc], Xw + grp*256);
    }
    __syncthreads();
    #pragma unroll
    for (int kk=0; kk<32; kk+=4){
      int G = kk>>2;
      float4 aa[8], bb[8];
      #pragma unroll
      for (int i=0;i<8;i++){ int r = ty+16*i; aa[i] = *(const float4*)&Xa[r*32 + 4*(G ^ (r&7))]; }
      #pragma unroll
      for (int j=0;j<8;j++){ int r = tx+16*j; bb[j] = *(const float4*)&Xw[r*32 + 4*(G ^ (r&7))]; }
      #pragma unroll
      for (int i=0;i<8;i++){
        #pragma unroll
        for (int j=0;j<8;j++){
          float a_ = acc[i][j];
          a_ = fmaf(aa[i].x, bb[j].x, a_);
          a_ = fmaf(aa[i].y, bb[j].y, a_);
          a_ = fmaf(aa[i].z, bb[j].z, a_);
          a_ = fmaf(aa[i].w, bb[j].w, a_);
          acc[i][j] = a_;
        }
      }
    }
  }
  #pragma unroll
  for (int i=0;i<8;i++){
    int m = m0 + ty + 16*i;
    #pragma unroll
    for (int j=0;j<8;j++){
      int o = o0 + tx + 16*j;
      float v = acc[i][j];
      if (o >= 256) v += bias[o - 256];
      OUT[((size_t)b*NPTS + m)*512 + o] = v;
    }
  }
}

// ---------------- GEMM (small, for sparse path) ----------------
__global__ __launch_bounds__(256) void k_gemm_pq(const float* __restrict__ A, const float* __restrict__ W,
                         const float* __restrict__ bias,
                         float* __restrict__ OUT, int M, int Ototal, int Ohalf){
  int b = blockIdx.z, mb = blockIdx.y, ob = blockIdx.x;
  int t = threadIdx.x; int tr = t&15, tc = t>>4;
  __shared__ float At[64][68], Wt[64][68];
  int m0 = mb*64, o0 = ob*64;
  float acc[4][4];
  #pragma unroll
  for(int i=0;i<4;i++){
    #pragma unroll
    for(int j=0;j<4;j++) acc[i][j]=0.f;
  }
  int li = t>>2, lk = (t&3)*16;
  for (int kt=0;kt<6;kt++){
    int k0 = kt*64;
    {
      int m = m0 + li;
      if (m < M){
        const float4* p = (const float4*)(A + ((size_t)b*M + m)*CUF + k0 + lk);
        #pragma unroll
        for (int e=0;e<4;e++) *(float4*)&At[li][lk+e*4] = p[e];
      } else {
        float4 z = make_float4(0.f,0.f,0.f,0.f);
        #pragma unroll
        for (int e=0;e<4;e++) *(float4*)&At[li][lk+e*4] = z;
      }
      const float4* pw = (const float4*)(W + (size_t)(o0+li)*CUF + k0 + lk);
      #pragma unroll
      for (int e=0;e<4;e++) *(float4*)&Wt[li][lk+e*4] = pw[e];
    }
    __syncthreads();
    #pragma unroll
    for (int k4=0;k4<16;k4++){
      float4 aa[4], bb[4];
      aa[0] = *(const float4*)&At[tr   ][k4*4];
      aa[1] = *(const float4*)&At[tr+16][k4*4];
      aa[2] = *(const float4*)&At[tr+32][k4*4];
      aa[3] = *(const float4*)&At[tr+48][k4*4];
      bb[0] = *(const float4*)&Wt[tc   ][k4*4];
      bb[1] = *(const float4*)&Wt[tc+16][k4*4];
      bb[2] = *(const float4*)&Wt[tc+32][k4*4];
      bb[3] = *(const float4*)&Wt[tc+48][k4*4];
      #pragma unroll
      for(int i=0;i<4;i++){
        #pragma unroll
        for(int j=0;j<4;j++)
          acc[i][j] += aa[i].x*bb[j].x + aa[i].y*bb[j].y + aa[i].z*bb[j].z + aa[i].w*bb[j].w;
      }
    }
    __syncthreads();
  }
  #pragma unroll
  for(int i=0;i<4;i++){
    int m = m0 + tr + 16*i;
    if (m < M){
      #pragma unroll
      for(int j=0;j<4;j++){
        int o = o0 + tc + 16*j;
        float v = acc[i][j];
        if (o >= Ohalf) v += bias[o - Ohalf];
        OUT[((size_t)b*M + m)*Ototal + o] = v;
      }
    }
  }
}

// ---------------- dense GCN gather + stats + max/min ----------------
__global__ __launch_bounds__(256) void k_gather_dn(const float* __restrict__ PQ, const int* __restrict__ idx,
                            float* __restrict__ dmax, float* __restrict__ dmin, double* __restrict__ part){
  int b = blockIdx.y, nb = blockIdx.x; int t = threadIdx.x;
  __shared__ int sidx[640];
  int n0 = nb*64;
  for (int k=t; k<640; k+=256) sidx[k] = idx[((size_t)b*NPTS + n0)*10 + k] & 2047;
  __syncthreads();
  double s=0.0, s2=0.0;
  const size_t pb = (size_t)b*NPTS*512;
  for (int n=0;n<64;n++){
    float qv = PQ[pb + (size_t)(n0+n)*512 + 256 + t];
    float mx = -3.4e38f, mn = 3.4e38f;
    #pragma unroll
    for (int k=0;k<10;k++){
      int m = sidx[n*10+k];
      float h = PQ[pb + (size_t)m*512 + t] + qv;
      mx = fmaxf(mx,h); mn = fminf(mn,h);
      s += h; s2 += (double)h*(double)h;
    }
    dmax[((size_t)b*NPTS + n0+n)*256 + t] = mx;
    dmin[((size_t)b*NPTS + n0+n)*256 + t] = mn;
  }
  size_t blk = (size_t)b*32 + nb;
  part[(blk*256 + t)*2] = s; part[(blk*256 + t)*2+1] = s2;
}

// ---------------- generic channel stats reduce -> (mean, invstd) ----------------
__global__ void k_reduce(const double* __restrict__ part, float* __restrict__ mv,
                         int nblk, int C, int count){
  int c = blockIdx.x; int t = threadIdx.x;
  double s=0.0, s2=0.0;
  for (int k=t;k<nblk;k+=64){ s += part[((size_t)k*C+c)*2]; s2 += part[((size_t)k*C+c)*2+1]; }
  #pragma unroll
  for (int off=32; off>=1; off>>=1){ s += __shfl_down(s, off, 64); s2 += __shfl_down(s2, off, 64); }
  if (t==0){
    double mean = s / (double)count;
    double var = s2 / (double)count - mean*mean;
    mv[c*2] = (float)mean;
    mv[c*2+1] = (float)(1.0 / sqrt(var + 1e-5));
  }
}

// ---------------- BN+act epilogue choosing max/min by sign(gamma); in-place on xmax ----------------
__global__ void k_epi(const float* __restrict__ xmin, float* __restrict__ xmax,
                      const float* __restrict__ mv, const float* __restrict__ g,
                      const float* __restrict__ be, int C, size_t total){
  size_t i = (size_t)blockIdx.x*256 + threadIdx.x;
  if (i>=total) return;
  int c = (int)(i % (size_t)C);
  float gg = g[c];
  float x = gg >= 0.f ? xmax[i] : xmin[i];
  float y = gg*(x - mv[c*2])*mv[c*2+1] + be[c];
  xmax[i] = lrelu(y);
}

// ---------------- d2s conv(1x3 valid) + stats + per-(b,c,s) max/min ----------------
__global__ __launch_bounds__(128) void k_d2s(const float* __restrict__ dense,
                      const float* __restrict__ w, const float* __restrict__ bias,
                      float* __restrict__ mx, float* __restrict__ mn, double* __restrict__ part){
  int b = blockIdx.y, s = blockIdx.x; int t = threadIdx.x; // 128
  __shared__ float IN[128*64];
  for (int k=0;k<64;k++){
    int f = t + k*128;
    int ci = f>>6, wj = f&63;
    IN[f] = dense[((size_t)b*128 + ci)*NPTS + s*64 + wj];
  }
  __syncthreads();
  float acc[62];
  float bv = bias[t];
  #pragma unroll
  for (int wj=0;wj<62;wj++) acc[wj]=bv;
  for (int ci=0;ci<128;ci++){
    const float* wp = w + ((size_t)t*128 + ci)*3;
    float w0 = wp[0], w1 = wp[1], w2 = wp[2];
    const float* row = &IN[ci*64];
    #pragma unroll
    for (int wj=0;wj<62;wj++) acc[wj] += row[wj]*w0 + row[wj+1]*w1 + row[wj+2]*w2;
  }
  float vmx=-3.4e38f, vmn=3.4e38f; double ss=0.0, ss2=0.0;
  #pragma unroll
  for (int wj=0;wj<62;wj++){ float v = acc[wj]; vmx=fmaxf(vmx,v); vmn=fminf(vmn,v); ss+=v; ss2+=(double)v*(double)v; }
  mx[((size_t)b*32+s)*128 + t] = vmx;
  mn[((size_t)b*32+s)*128 + t] = vmn;
  part[(((size_t)b*32+s)*128 + t)*2] = ss; part[(((size_t)b*32+s)*128 + t)*2+1] = ss2;
}

// ---------------- build union_sparse points Xs f32 [8][32][384] ----------------
__global__ void k_build_xs(const float* __restrict__ sparse,
                           const float* __restrict__ mx, const float* __restrict__ mn,
                           const float* __restrict__ mv, const float* __restrict__ g,
                           const float* __restrict__ be, float* __restrict__ Xs){
  int b = blockIdx.x; int c = threadIdx.x; // 384
  for (int n=0;n<32;n++){
    float v;
    if (c < 256) v = sparse[((size_t)b*256 + c)*32 + n];
    else {
      int cc = c-256;
      float gg = g[cc];
      float x = gg>=0.f ? mx[((size_t)b*32+n)*128+cc] : mn[((size_t)b*32+n)*128+cc];
      v = lrelu(gg*(x - mv[cc*2])*mv[cc*2+1] + be[cc]);
    }
    Xs[((size_t)b*32+n)*384 + c] = v;
  }
}

// ---------------- sparse kNN (k=2 of 32) ----------------
__global__ __launch_bounds__(256) void k_knn_sp(const float* __restrict__ Xs, int* __restrict__ idx){
  int b = blockIdx.x; int t = threadIdx.x;
  __shared__ float Xh[32*388];
  __shared__ float snl[32];
  __shared__ float D[32*33];
  for (int k=t;k<32*384;k+=256){ int n=k/384, c=k-n*384; Xh[n*388+c] = Xs[(size_t)b*32*384 + k]; }
  __syncthreads();
  if (t<32){ double s=0.0; for (int c=0;c<384;c++){ double v=(double)Xh[t*388+c]; s+=v*v; } snl[t]=(float)s; }
  __syncthreads();
  for (int p=t;p<1024;p+=256){
    int n=p>>5, m=p&31;
    const float* A=&Xh[n*388]; const float* B=&Xh[m*388];
    double s=0.0;
    for (int c=0;c<384;c++) s += (double)A[c]*(double)B[c];
    D[n*33+m] = (float)((double)snl[m] - 2.0*s);
  }
  __syncthreads();
  if (t<32){
    float v0=3.4e38f,v1=3.4e38f; int i0=0,i1=0;
    for (int m=0;m<32;m++){
      float v=D[t*33+m];
      if (v < v0){ v1=v0;i1=i0; v0=v;i0=m; }
      else if (v < v1){ v1=v;i1=m; }
    }
    idx[((size_t)b*32+t)*2]=i0; idx[((size_t)b*32+t)*2+1]=i1;
  }
}

// ---------------- sparse GCN gather + stats + max/min ----------------
__global__ void k_gather_sp(const float* __restrict__ PQ, const int* __restrict__ idx,
                            float* __restrict__ umax, float* __restrict__ umin, double* __restrict__ part){
  int b = blockIdx.x; int t = threadIdx.x; // 512
  double s=0.0, s2=0.0;
  for (int n=0;n<32;n++){
    float qv = PQ[((size_t)b*32+n)*1024 + 512 + t];
    float mxv=-3.4e38f, mnv=3.4e38f;
    #pragma unroll
    for (int k=0;k<2;k++){
      int m = idx[((size_t)b*32+n)*2+k] & 31;
      float h = PQ[((size_t)b*32+m)*1024 + t] + qv;
      mxv=fmaxf(mxv,h); mnv=fminf(mnv,h); s+=h; s2+=(double)h*(double)h;
    }
    umax[((size_t)b*32+n)*512+t]=mxv; umin[((size_t)b*32+n)*512+t]=mnv;
  }
  part[((size_t)b*512+t)*2]=s; part[((size_t)b*512+t)*2+1]=s2;
}

// ---------------- FPS (16 of 32) ----------------
__global__ void k_fps(const float* __restrict__ coor, int* __restrict__ fps){
  int b = blockIdx.x; int t = threadIdx.x; // 64
  __shared__ float C[32*64]; __shared__ float dist[32]; __shared__ int fs;
  for (int k=t;k<2048;k+=64) C[k] = coor[(size_t)b*2048 + k];
  if (t<32) dist[t]=1e10f;
  if (t==0) fs=0;
  __syncthreads();
  for (int it=0; it<16; it++){
    int f = fs;
    if (t==0) fps[b*16+it] = f;
    if (t<32){
      float d=0.f;
      for (int c=0;c<64;c++){ float df = C[t*64+c]-C[f*64+c]; d += df*df; }
      dist[t] = fminf(dist[t], d);
    }
    __syncthreads();
    if (t==0){
      float bd=-1.f; int bi=0;
      for (int n=0;n<32;n++){ if (dist[n]>bd){bd=dist[n];bi=n;} }
      fs=bi;
    }
    __syncthreads();
  }
}

// ---------------- outputs 0 and 2 ----------------
__global__ void k_out0(const float* __restrict__ usp, const int* __restrict__ fps, float* __restrict__ out0){
  int b = blockIdx.y, s = blockIdx.x; int t = threadIdx.x; // 512
  int n = fps[b*16+s] & 31;
  out0[((size_t)b*512 + t)*16 + s] = usp[((size_t)b*32+n)*512 + t];
}
__global__ void k_out2(const float* __restrict__ coor, const int* __restrict__ fps, float* __restrict__ out2){
  int b = blockIdx.x; int t = threadIdx.x; // 256
  for (int e=t; e<1024; e+=256){
    int s=e>>6, c=e&63;
    out2[(size_t)b*1024 + e] = coor[((size_t)b*32 + (fps[b*16+s]&31))*64 + c];
  }
}

// ---------------- dcv conv (1x3, stride 2, pad 1) on gathered sticks; 2-pass over ci ----------------
__global__ __launch_bounds__(256) void k_dcv(const float* __restrict__ gdn, const int* __restrict__ fps,
                      const float* __restrict__ w, const float* __restrict__ bias,
                      float* __restrict__ pre, double* __restrict__ part){
  int b = blockIdx.y, s = blockIdx.x; int t = threadIdx.x; // 256
  __shared__ float I[64*128];  // 32 KB
  int n0 = (fps[b*16+s] & 31)*64;
  const size_t gbase = ((size_t)b*NPTS + n0)*256;
  float acc[32];
  float bv = bias[t];
  #pragma unroll
  for (int q=0;q<32;q++) acc[q]=bv;
  for (int half=0; half<2; half++){
    int cbase = half*128;
    __syncthreads();
    for (int e=t; e<8192; e+=256){
      int p = e>>7, c = e&127;
      I[e] = gdn[gbase + (size_t)p*256 + cbase + c];
    }
    __syncthreads();
    for (int ci=0; ci<128; ci+=4){
      float wv[4][3];
      const float* wp = w + ((size_t)t*256 + cbase + ci)*3;
      #pragma unroll
      for (int q=0;q<4;q++){ wv[q][0]=wp[q*3]; wv[q][1]=wp[q*3+1]; wv[q][2]=wp[q*3+2]; }
      #pragma unroll
      for (int q=0;q<32;q++){
        float4 ev = *(const float4*)&I[(2*q)*128 + ci];
        acc[q] += ev.x*wv[0][1] + ev.y*wv[1][1] + ev.z*wv[2][1] + ev.w*wv[3][1];
        float4 ov = *(const float4*)&I[(2*q+1)*128 + ci];
        acc[q] += ov.x*wv[0][2] + ov.y*wv[1][2] + ov.z*wv[2][2] + ov.w*wv[3][2];
        if (q < 31) acc[q+1] += ov.x*wv[0][0] + ov.y*wv[1][0] + ov.z*wv[2][0] + ov.w*wv[3][0];
      }
    }
  }
  double ss=0.0, ss2=0.0;
  #pragma unroll
  for (int q=0;q<32;q++){ ss += acc[q]; ss2 += (double)acc[q]*(double)acc[q]; }
  float* o = pre + (((size_t)b*256 + t)*16 + s)*32;
  #pragma unroll
  for (int q=0;q<32;q++) o[q] = acc[q];
  part[(((size_t)b*16+s)*256 + t)*2] = ss; part[(((size_t)b*16+s)*256 + t)*2+1] = ss2;
}

__global__ void k_epi_dcv(const float* __restrict__ pre, const float* __restrict__ mv,
                          const float* __restrict__ g, const float* __restrict__ be,
                          float* __restrict__ out1){
  size_t i = (size_t)blockIdx.x*256 + threadIdx.x; // 1,048,576
  int c = (int)((i>>9) & 255);
  float gg = g[c];
  float y = gg*(pre[i]-mv[c*2])*mv[c*2+1] + be[c];
  out1[i] = lrelu(y);
}

extern "C" void kernel_launch(void* const* d_in, const int* in_sizes, int n_in,
                              void* d_out, int out_size, void* d_ws, size_t ws_size,
                              hipStream_t stream){
  const float* sparse = (const float*)d_in[0];
  const float* dense  = (const float*)d_in[1];
  const float* coor   = (const float*)d_in[2];
  const float* d2s_w  = (const float*)d_in[3];
  const float* d2s_b  = (const float*)d_in[4];
  const float* d2s_g  = (const float*)d_in[5];
  const float* d2s_be = (const float*)d_in[6];
  const float* gsp_w  = (const float*)d_in[7];
  const float* gsp_b  = (const float*)d_in[8];
  const float* gsp_g  = (const float*)d_in[9];
  const float* gsp_be = (const float*)d_in[10];
  const float* gdn_w  = (const float*)d_in[11];
  const float* gdn_b  = (const float*)d_in[12];
  const float* gdn_g  = (const float*)d_in[13];
  const float* gdn_be = (const float*)d_in[14];
  const float* dcv_w  = (const float*)d_in[15];
  const float* dcv_b  = (const float*)d_in[16];
  const float* dcv_g  = (const float*)d_in[17];
  const float* dcv_be = (const float*)d_in[18];

  float* out0 = (float*)d_out;
  float* out1 = out0 + 8*512*16;
  float* out2 = out1 + (size_t)8*256*512;

  char* base = (char*)d_ws; size_t off = 0;
  auto alloc = [&](size_t bytes)->void*{ void* p = base + off; off += (bytes + 255) & ~(size_t)255; return p; };
  float* Xdn  = (float*)alloc((size_t)8*2048*384*4);
  float* sn   = (float*)alloc((size_t)8*2048*4);
  int*   idxd = (int*)alloc((size_t)8*2048*10*4);
  float* PQ   = (float*)alloc((size_t)8*2048*512*4);
  float* dmax = (float*)alloc((size_t)8*2048*256*4);
  float* dmin = (float*)alloc((size_t)8*2048*256*4);
  double* partdn = (double*)alloc((size_t)256*256*2*8);
  float* mvdn = (float*)alloc(256*2*4);
  float* Wcd  = (float*)alloc((size_t)512*384*4);
  float* Wcs  = (float*)alloc((size_t)1024*384*4);
  float* Xs   = (float*)alloc((size_t)8*32*384*4);
  int*   idxs = (int*)alloc(8*32*2*4);
  float* PQs  = (float*)alloc((size_t)8*32*1024*4);
  float* umax = (float*)alloc((size_t)8*32*512*4);
  float* umin = (float*)alloc((size_t)8*32*512*4);
  double* partsp = (double*)alloc((size_t)8*512*2*8);
  float* mvsp = (float*)alloc(512*2*4);
  float* d2mx = (float*)alloc((size_t)8*32*128*4);
  float* d2mn = (float*)alloc((size_t)8*32*128*4);
  double* partd2 = (double*)alloc((size_t)256*128*2*8);
  float* mvd2 = (float*)alloc(128*2*4);
  int* fps = (int*)alloc(8*16*4);
  float* dcvpre = (float*)alloc((size_t)8*256*512*4);
  double* partdcv = (double*)alloc((size_t)128*256*2*8);
  float* mvdcv = (float*)alloc(256*2*4);
  if (off > ws_size) return;  // diagnostic: output stays zero -> ws too small

  // Dot (4 batches x 2048 x 2048 f32 = 67.1 MB) overlays PQ..mvdcv (~73 MB):
  // everything in that region is written only AFTER k_sel consumed Dot.
  float* Dot = PQ;

  k_build_xdn<<<dim3(32,8), 256, 0, stream>>>(dense, sparse, Xdn);
  k_sn<<<64, 256, 0, stream>>>(Xdn, sn);
  k_dist_tri<<<dim3(136,1,4), 256, 0, stream>>>(Xdn, Dot, 0);
  k_sel<<<2048, 256, 0, stream>>>(Dot, sn, idxd, 0);
  k_dist_tri<<<dim3(136,1,4), 256, 0, stream>>>(Xdn, Dot, 4);
  k_sel<<<2048, 256, 0, stream>>>(Dot, sn, idxd, 4);
  k_prepw<<<768, 256, 0, stream>>>(gdn_w, Wcd, 256);
  k_prepw<<<1536, 256, 0, stream>>>(gsp_w, Wcs, 512);
  k_gemm_pq2<<<dim3(4,16,8), 256, 0, stream>>>(Xdn, Wcd, gdn_b, PQ);
  k_gather_dn<<<dim3(32,8), 256, 0, stream>>>(PQ, idxd, dmax, dmin, partdn);
  k_reduce<<<256, 64, 0, stream>>>(partdn, mvdn, 256, 256, 163840);
  k_epi<<<16384, 256, 0, stream>>>(dmin, dmax, mvdn, gdn_g, gdn_be, 256, (size_t)8*2048*256);
  k_d2s<<<dim3(32,8), 128, 0, stream>>>(dense, d2s_w, d2s_b, d2mx, d2mn, partd2);
  k_reduce<<<128, 64, 0, stream>>>(partd2, mvd2, 256, 128, 15872);
  k_build_xs<<<8, 384, 0, stream>>>(sparse, d2mx, d2mn, mvd2, d2s_g, d2s_be, Xs);
  k_knn_sp<<<8, 256, 0, stream>>>(Xs, idxs);
  k_gemm_pq<<<dim3(16,1,8), 256, 0, stream>>>(Xs, Wcs, gsp_b, PQs, 32, 1024, 512);
  k_gather_sp<<<8, 512, 0, stream>>>(PQs, idxs, umax, umin, partsp);
  k_reduce<<<512, 64, 0, stream>>>(partsp, mvsp, 8, 512, 512);
  k_epi<<<512, 256, 0, stream>>>(umin, umax, mvsp, gsp_g, gsp_be, 512, (size_t)8*32*512);
  k_fps<<<8, 64, 0, stream>>>(coor, fps);
  k_out0<<<dim3(16,8), 512, 0, stream>>>(umax, fps, out0);
  k_out2<<<8, 256, 0, stream>>>(coor, fps, out2);
  k_dcv<<<dim3(16,8), 256, 0, stream>>>(dmax, fps, dcv_w, dcv_b, dcvpre, partdcv);
  k_reduce<<<256, 64, 0, stream>>>(partdcv, mvdcv, 128, 256, 4096);
  k_epi_dcv<<<4096, 256, 0, stream>>>(dcvpre, mvdcv, dcv_g, dcv_be, out1);
}

// Round 16
// 760.158 us; speedup vs baseline: 2.0613x; 1.0996x over previous
//
#include <hip/hip_runtime.h>

#define NPTS 2048
#define CUF 384

__device__ __forceinline__ float lrelu(float y){ return y>=0.f ? y : 0.2f*y; }

// async global->LDS, 16B per lane; LDS dest = wave-uniform base + lane*16
#define GLD16(g, l) __builtin_amdgcn_global_load_lds( \
    (const __attribute__((address_space(1))) void*)(g), \
    (__attribute__((address_space(3))) void*)(l), 16, 0, 0)

// ---------------- build X_dn (point-major f32 [8][2048][384]) ----------------
__global__ void k_build_xdn(const float* __restrict__ dense,
                            const float* __restrict__ sparse,
                            float* __restrict__ X){
  int b = blockIdx.y, ch = blockIdx.x;  // ch = stick 0..31 (64 points)
  int t = threadIdx.x;                  // 256
  __shared__ float tile[64*128];        // 32 KB
  for (int k=0;k<32;k++){
    int f = t + k*256;                  // f = c*64 + j, c<128
    int c = f>>6, j = f&63;
    tile[j*128 + c] = dense[((size_t)b*128 + c)*NPTS + ch*64 + j];
  }
  __syncthreads();
  for (int k=0;k<32;k++){
    int f = t + k*256;                  // f = j*128 + c
    int j = f>>7, c = f&127;
    X[((size_t)b*NPTS + ch*64 + j)*CUF + c] = tile[f];
  }
  float v = sparse[((size_t)b*256 + t)*32 + ch];
  for (int j=0;j<64;j++) X[((size_t)b*NPTS + ch*64 + j)*CUF + 128 + t] = v;
}

// ---------------- row sum-of-squares, numpy-pairwise mimic ----------------
__global__ void k_sn(const float* __restrict__ X, float* __restrict__ sn){
  int g = blockIdx.x*256 + threadIdx.x;   // 16384 = 8*2048 points
  if (g >= 8*NPTS) return;
  const float* row = X + (size_t)g*CUF;
  float blk[4];
  #pragma unroll
  for (int bI=0;bI<4;bI++){
    const float* p = row + bI*96;
    float r[8];
    #pragma unroll
    for (int l=0;l<8;l++) r[l] = __fmul_rn(p[l], p[l]);
    #pragma unroll 1
    for (int i=8;i<96;i+=8){
      #pragma unroll
      for (int l=0;l<8;l++) r[l] = __fadd_rn(r[l], __fmul_rn(p[i+l], p[i+l]));
    }
    float s01 = __fadd_rn(r[0], r[1]);
    float s23 = __fadd_rn(r[2], r[3]);
    float s45 = __fadd_rn(r[4], r[5]);
    float s67 = __fadd_rn(r[6], r[7]);
    blk[bI] = __fadd_rn(__fadd_rn(s01, s23), __fadd_rn(s45, s67));
  }
  sn[g] = __fadd_rn(__fadd_rn(blk[0], blk[1]), __fadd_rn(blk[2], blk[3]));
}

// ---------------- triangular dot tiles -> global Dot[bb][r][c] ----------------
__global__ __launch_bounds__(256) void k_dist_tri(
    const float* __restrict__ X, float* __restrict__ Dot, int b_base){
  int z = blockIdx.z; int b = b_base + z;
  int t = threadIdx.x;
  int tx = t & 15, ty = t >> 4;
  int idx = blockIdx.x, rb = 0;
  while (idx >= 16 - rb){ idx -= 16 - rb; rb++; }
  int cb = rb + idx;
  __shared__ float U[8448];          // staging; Ds[128][65] aliases
  float* Xr = U;
  float* Xc = U + 4096;
  float* Ds = U;
  int r0 = rb*128;
  int c0 = cb*128;
  const size_t xb = (size_t)b*NPTS*CUF;
  const size_t zb = (size_t)z*NPTS*NPTS;

  int wv  = t >> 6;
  int sub = (t & 63) >> 3;
  int gs  = t & 7;
  int rowsA[4]; int swzA[4];
  #pragma unroll
  for (int cc=0;cc<4;cc++){
    int grp = wv*4 + cc;
    int row = grp*8 + sub;
    rowsA[cc] = row;
    swzA[cc] = 4*(gs ^ (row&7));
  }

  float acc[8][8];
  #pragma unroll
  for (int i=0;i<8;i++){
    #pragma unroll
    for (int j=0;j<8;j++) acc[i][j] = 0.f;
  }
  for (int kt=0; kt<12; kt++){
    int k0 = kt*32;
    __syncthreads();
    #pragma unroll
    for (int cc=0;cc<4;cc++){
      int grp = wv*4 + cc;
      GLD16(X + xb + (size_t)(r0+rowsA[cc])*CUF + k0 + swzA[cc], Xr + grp*256);
      GLD16(X + xb + (size_t)(c0+rowsA[cc])*CUF + k0 + swzA[cc], Xc + grp*256);
    }
    __syncthreads();
    #pragma unroll
    for (int kk=0; kk<32; kk+=4){
      int G = kk>>2;
      float4 aa[8], bb[8];
      #pragma unroll
      for (int i=0;i<8;i++){ int r = ty+16*i; aa[i] = *(const float4*)&Xr[r*32 + 4*(G ^ (r&7))]; }
      #pragma unroll
      for (int j=0;j<8;j++){ int r = tx+16*j; bb[j] = *(const float4*)&Xc[r*32 + 4*(G ^ (r&7))]; }
      #pragma unroll
      for (int i=0;i<8;i++){
        #pragma unroll
        for (int j=0;j<8;j++){
          float a_ = acc[i][j];
          a_ = fmaf(aa[i].x, bb[j].x, a_);
          a_ = fmaf(aa[i].y, bb[j].y, a_);
          a_ = fmaf(aa[i].z, bb[j].z, a_);
          a_ = fmaf(aa[i].w, bb[j].w, a_);
          acc[i][j] = a_;
        }
      }
    }
  }
  // row region
  #pragma unroll
  for (int i=0;i<8;i++){
    size_t rbase = zb + (size_t)(r0 + ty + 16*i)*NPTS + c0;
    #pragma unroll
    for (int j=0;j<8;j++) Dot[rbase + tx + 16*j] = acc[i][j];
  }
  // transposed region (off-diagonal)
  if (rb != cb){
    for (int h=0; h<2; h++){
      __syncthreads();
      #pragma unroll
      for (int i2=0;i2<4;i2++){
        #pragma unroll
        for (int j=0;j<8;j++){
          Ds[(tx+16*j)*65 + ty + 16*i2] = acc[h*4+i2][j];
        }
      }
      __syncthreads();
      for (int e=t; e<128*64; e+=256){
        int col = e>>6, rr = e&63;
        Dot[zb + (size_t)(c0+col)*NPTS + r0 + h*64 + rr] = Ds[col*65 + rr];
      }
    }
  }
}

// ---------------- whole-row top-10: one wave per row, u64-key wave-min ----------------
__global__ __launch_bounds__(256) void k_sel(const float* __restrict__ Dot,
                                             const float* __restrict__ sn,
                                             int* __restrict__ idx, int b_base){
  int t = threadIdx.x;
  int lane = t & 63, w = t >> 6;
  int rglob = blockIdx.x*4 + w;          // 0..8191
  int bb = rglob >> 11;
  int r  = rglob & 2047;
  int b  = b_base + bb;
  const float* drow = Dot + ((size_t)bb*NPTS + r)*NPTS;
  const float* snp  = sn + (size_t)b*NPTS;
  float snr = snp[r];
  unsigned long long key[32];
  #pragma unroll
  for (int k=0;k<8;k++){
    int cbase = k*256 + lane*4;          // coalesced: wave covers contiguous 1KB
    float4 dd = *(const float4*)&drow[cbase];
    float4 ss = *(const float4*)&snp[cbase];
    float v0 = __fsub_rn(__fadd_rn(snr, ss.x), __fmul_rn(2.0f, dd.x));
    float v1 = __fsub_rn(__fadd_rn(snr, ss.y), __fmul_rn(2.0f, dd.y));
    float v2 = __fsub_rn(__fadd_rn(snr, ss.z), __fmul_rn(2.0f, dd.z));
    float v3 = __fsub_rn(__fadd_rn(snr, ss.w), __fmul_rn(2.0f, dd.w));
    float vv[4] = {v0, v1, v2, v3};
    #pragma unroll
    for (int u=0;u<4;u++){
      unsigned int bits = __float_as_uint(vv[u]);
      unsigned int flip = bits ^ ((unsigned int)((int)bits >> 31) | 0x80000000u);
      key[k*4+u] = ((unsigned long long)flip << 32) | (unsigned int)(cbase + u);
    }
  }
  unsigned long long last = 0ull;
  int out[10];
  #pragma unroll
  for (int q=0;q<10;q++){
    const unsigned long long INF = 0xFFFFFFFFFFFFFFFFull;
    unsigned long long m0[16];
    #pragma unroll
    for (int s=0;s<16;s++){
      unsigned long long a = (key[s]    > last) ? key[s]    : INF;
      unsigned long long c = (key[s+16] > last) ? key[s+16] : INF;
      m0[s] = (c < a) ? c : a;
    }
    #pragma unroll
    for (int s=0;s<8;s++) m0[s] = (m0[s+8] < m0[s]) ? m0[s+8] : m0[s];
    #pragma unroll
    for (int s=0;s<4;s++) m0[s] = (m0[s+4] < m0[s]) ? m0[s+4] : m0[s];
    m0[0] = (m0[2] < m0[0]) ? m0[2] : m0[0];
    m0[1] = (m0[3] < m0[1]) ? m0[3] : m0[1];
    unsigned long long m = (m0[1] < m0[0]) ? m0[1] : m0[0];
    #pragma unroll
    for (int sh=1; sh<64; sh<<=1){
      unsigned long long o = (unsigned long long)__shfl_xor((long long)m, sh, 64);
      m = (o < m) ? o : m;
    }
    last = m;
    out[q] = (int)(m & 0xFFFFFFFFull);
  }
  if (lane == 0){
    int* o = idx + ((size_t)b*NPTS + r)*10;
    #pragma unroll
    for (int q=0;q<10;q++) o[q] = out[q];
  }
}

// ---------------- W -> [W1 ; W2-W1] ----------------
__global__ void k_prepw(const float* __restrict__ Wsrc, float* __restrict__ Wcat, int Ohalf){
  int g = blockIdx.x*256 + threadIdx.x;
  int total = Ohalf*2*CUF;
  if (g >= total) return;
  int o = g / CUF, c = g % CUF;
  float v;
  if (o < Ohalf) v = Wsrc[(size_t)o*768 + c];
  else { int oo = o - Ohalf; v = Wsrc[(size_t)oo*768 + 384 + c] - Wsrc[(size_t)oo*768 + c]; }
  Wcat[g] = v;
}

// ---------------- dense GEMM 128x128x(BK=32), gload_lds staging ----------------
__global__ __launch_bounds__(256) void k_gemm_pq2(const float* __restrict__ A, const float* __restrict__ W,
                         const float* __restrict__ bias, float* __restrict__ OUT){
  int b = blockIdx.z, mb = blockIdx.y, ob = blockIdx.x;   // (4,16,8)
  int t = threadIdx.x; int tx = t&15, ty = t>>4;
  __shared__ float Xa[4096];
  __shared__ float Xw[4096];
  int m0 = mb*128, o0 = ob*128;
  float acc[8][8];
  #pragma unroll
  for (int i=0;i<8;i++){
    #pragma unroll
    for (int j=0;j<8;j++) acc[i][j] = 0.f;
  }
  int wv  = t >> 6;
  int sub = (t & 63) >> 3;
  int gs  = t & 7;
  int rowsA[4]; int swzA[4];
  #pragma unroll
  for (int cc=0;cc<4;cc++){
    int grp = wv*4 + cc;
    int row = grp*8 + sub;
    rowsA[cc] = row;
    swzA[cc] = 4*(gs ^ (row&7));
  }
  for (int kt=0; kt<12; kt++){
    int k0 = kt*32;
    __syncthreads();
    #pragma unroll
    for (int cc=0;cc<4;cc++){
      int grp = wv*4 + cc;
      GLD16(A + ((size_t)b*NPTS + m0 + rowsA[cc])*CUF + k0 + swzA[cc], Xa + grp*256);
      GLD16(W + (size_t)(o0 + rowsA[cc])*CUF + k0 + swzA[cc], Xw + grp*256);
    }
    __syncthreads();
    #pragma unroll
    for (int kk=0; kk<32; kk+=4){
      int G = kk>>2;
      float4 aa[8], bb[8];
      #pragma unroll
      for (int i=0;i<8;i++){ int r = ty+16*i; aa[i] = *(const float4*)&Xa[r*32 + 4*(G ^ (r&7))]; }
      #pragma unroll
      for (int j=0;j<8;j++){ int r = tx+16*j; bb[j] = *(const float4*)&Xw[r*32 + 4*(G ^ (r&7))]; }
      #pragma unroll
      for (int i=0;i<8;i++){
        #pragma unroll
        for (int j=0;j<8;j++){
          float a_ = acc[i][j];
          a_ = fmaf(aa[i].x, bb[j].x, a_);
          a_ = fmaf(aa[i].y, bb[j].y, a_);
          a_ = fmaf(aa[i].z, bb[j].z, a_);
          a_ = fmaf(aa[i].w, bb[j].w, a_);
          acc[i][j] = a_;
        }
      }
    }
  }
  #pragma unroll
  for (int i=0;i<8;i++){
    int m = m0 + ty + 16*i;
    #pragma unroll
    for (int j=0;j<8;j++){
      int o = o0 + tx + 16*j;
      float v = acc[i][j];
      if (o >= 256) v += bias[o - 256];
      OUT[((size_t)b*NPTS + m)*512 + o] = v;
    }
  }
}

// ---------------- GEMM (small, for sparse path) ----------------
__global__ __launch_bounds__(256) void k_gemm_pq(const float* __restrict__ A, const float* __restrict__ W,
                         const float* __restrict__ bias,
                         float* __restrict__ OUT, int M, int Ototal, int Ohalf){
  int b = blockIdx.z, mb = blockIdx.y, ob = blockIdx.x;
  int t = threadIdx.x; int tr = t&15, tc = t>>4;
  __shared__ float At[64][68], Wt[64][68];
  int m0 = mb*64, o0 = ob*64;
  float acc[4][4];
  #pragma unroll
  for(int i=0;i<4;i++){
    #pragma unroll
    for(int j=0;j<4;j++) acc[i][j]=0.f;
  }
  int li = t>>2, lk = (t&3)*16;
  for (int kt=0;kt<6;kt++){
    int k0 = kt*64;
    {
      int m = m0 + li;
      if (m < M){
        const float4* p = (const float4*)(A + ((size_t)b*M + m)*CUF + k0 + lk);
        #pragma unroll
        for (int e=0;e<4;e++) *(float4*)&At[li][lk+e*4] = p[e];
      } else {
        float4 z = make_float4(0.f,0.f,0.f,0.f);
        #pragma unroll
        for (int e=0;e<4;e++) *(float4*)&At[li][lk+e*4] = z;
      }
      const float4* pw = (const float4*)(W + (size_t)(o0+li)*CUF + k0 + lk);
      #pragma unroll
      for (int e=0;e<4;e++) *(float4*)&Wt[li][lk+e*4] = pw[e];
    }
    __syncthreads();
    #pragma unroll
    for (int k4=0;k4<16;k4++){
      float4 aa[4], bb[4];
      aa[0] = *(const float4*)&At[tr   ][k4*4];
      aa[1] = *(const float4*)&At[tr+16][k4*4];
      aa[2] = *(const float4*)&At[tr+32][k4*4];
      aa[3] = *(const float4*)&At[tr+48][k4*4];
      bb[0] = *(const float4*)&Wt[tc   ][k4*4];
      bb[1] = *(const float4*)&Wt[tc+16][k4*4];
      bb[2] = *(const float4*)&Wt[tc+32][k4*4];
      bb[3] = *(const float4*)&Wt[tc+48][k4*4];
      #pragma unroll
      for(int i=0;i<4;i++){
        #pragma unroll
        for(int j=0;j<4;j++)
          acc[i][j] += aa[i].x*bb[j].x + aa[i].y*bb[j].y + aa[i].z*bb[j].z + aa[i].w*bb[j].w;
      }
    }
    __syncthreads();
  }
  #pragma unroll
  for(int i=0;i<4;i++){
    int m = m0 + tr + 16*i;
    if (m < M){
      #pragma unroll
      for(int j=0;j<4;j++){
        int o = o0 + tc + 16*j;
        float v = acc[i][j];
        if (o >= Ohalf) v += bias[o - Ohalf];
        OUT[((size_t)b*M + m)*Ototal + o] = v;
      }
    }
  }
}

// ---------------- dense GCN gather + stats + max/min ----------------
__global__ __launch_bounds__(256) void k_gather_dn(const float* __restrict__ PQ, const int* __restrict__ idx,
                            float* __restrict__ dmax, float* __restrict__ dmin, double* __restrict__ part){
  int b = blockIdx.y, nb = blockIdx.x; int t = threadIdx.x;
  __shared__ int sidx[640];
  int n0 = nb*64;
  for (int k=t; k<640; k+=256) sidx[k] = idx[((size_t)b*NPTS + n0)*10 + k] & 2047;
  __syncthreads();
  double s=0.0, s2=0.0;
  const size_t pb = (size_t)b*NPTS*512;
  for (int n=0;n<64;n++){
    float qv = PQ[pb + (size_t)(n0+n)*512 + 256 + t];
    float mx = -3.4e38f, mn = 3.4e38f;
    #pragma unroll
    for (int k=0;k<10;k++){
      int m = sidx[n*10+k];
      float h = PQ[pb + (size_t)m*512 + t] + qv;
      mx = fmaxf(mx,h); mn = fminf(mn,h);
      s += h; s2 += (double)h*(double)h;
    }
    dmax[((size_t)b*NPTS + n0+n)*256 + t] = mx;
    dmin[((size_t)b*NPTS + n0+n)*256 + t] = mn;
  }
  size_t blk = (size_t)b*32 + nb;
  part[(blk*256 + t)*2] = s; part[(blk*256 + t)*2+1] = s2;
}

// ---------------- generic channel stats reduce -> (mean, invstd) ----------------
__global__ void k_reduce(const double* __restrict__ part, float* __restrict__ mv,
                         int nblk, int C, int count){
  int c = blockIdx.x; int t = threadIdx.x;
  double s=0.0, s2=0.0;
  for (int k=t;k<nblk;k+=64){ s += part[((size_t)k*C+c)*2]; s2 += part[((size_t)k*C+c)*2+1]; }
  #pragma unroll
  for (int off=32; off>=1; off>>=1){ s += __shfl_down(s, off, 64); s2 += __shfl_down(s2, off, 64); }
  if (t==0){
    double mean = s / (double)count;
    double var = s2 / (double)count - mean*mean;
    mv[c*2] = (float)mean;
    mv[c*2+1] = (float)(1.0 / sqrt(var + 1e-5));
  }
}

// ---------------- BN+act epilogue choosing max/min by sign(gamma); in-place on xmax ----------------
__global__ void k_epi(const float* __restrict__ xmin, float* __restrict__ xmax,
                      const float* __restrict__ mv, const float* __restrict__ g,
                      const float* __restrict__ be, int C, size_t total){
  size_t i = (size_t)blockIdx.x*256 + threadIdx.x;
  if (i>=total) return;
  int c = (int)(i % (size_t)C);
  float gg = g[c];
  float x = gg >= 0.f ? xmax[i] : xmin[i];
  float y = gg*(x - mv[c*2])*mv[c*2+1] + be[c];
  xmax[i] = lrelu(y);
}

// ---------------- d2s conv(1x3 valid) + stats + per-(b,c,s) max/min ----------------
__global__ __launch_bounds__(128) void k_d2s(const float* __restrict__ dense,
                      const float* __restrict__ w, const float* __restrict__ bias,
                      float* __restrict__ mx, float* __restrict__ mn, double* __restrict__ part){
  int b = blockIdx.y, s = blockIdx.x; int t = threadIdx.x; // 128
  __shared__ float IN[128*64];
  for (int k=0;k<64;k++){
    int f = t + k*128;
    int ci = f>>6, wj = f&63;
    IN[f] = dense[((size_t)b*128 + ci)*NPTS + s*64 + wj];
  }
  __syncthreads();
  float acc[62];
  float bv = bias[t];
  #pragma unroll
  for (int wj=0;wj<62;wj++) acc[wj]=bv;
  for (int ci=0;ci<128;ci++){
    const float* wp = w + ((size_t)t*128 + ci)*3;
    float w0 = wp[0], w1 = wp[1], w2 = wp[2];
    const float* row = &IN[ci*64];
    #pragma unroll
    for (int wj=0;wj<62;wj++) acc[wj] += row[wj]*w0 + row[wj+1]*w1 + row[wj+2]*w2;
  }
  float vmx=-3.4e38f, vmn=3.4e38f; double ss=0.0, ss2=0.0;
  #pragma unroll
  for (int wj=0;wj<62;wj++){ float v = acc[wj]; vmx=fmaxf(vmx,v); vmn=fminf(vmn,v); ss+=v; ss2+=(double)v*(double)v; }
  mx[((size_t)b*32+s)*128 + t] = vmx;
  mn[((size_t)b*32+s)*128 + t] = vmn;
  part[(((size_t)b*32+s)*128 + t)*2] = ss; part[(((size_t)b*32+s)*128 + t)*2+1] = ss2;
}

// ---------------- build union_sparse points Xs f32 [8][32][384] ----------------
__global__ void k_build_xs(const float* __restrict__ sparse,
                           const float* __restrict__ mx, const float* __restrict__ mn,
                           const float* __restrict__ mv, const float* __restrict__ g,
                           const float* __restrict__ be, float* __restrict__ Xs){
  int b = blockIdx.x; int c = threadIdx.x; // 384
  for (int n=0;n<32;n++){
    float v;
    if (c < 256) v = sparse[((size_t)b*256 + c)*32 + n];
    else {
      int cc = c-256;
      float gg = g[cc];
      float x = gg>=0.f ? mx[((size_t)b*32+n)*128+cc] : mn[((size_t)b*32+n)*128+cc];
      v = lrelu(gg*(x - mv[cc*2])*mv[cc*2+1] + be[cc]);
    }
    Xs[((size_t)b*32+n)*384 + c] = v;
  }
}

// ---------------- sparse kNN (k=2 of 32) ----------------
__global__ __launch_bounds__(256) void k_knn_sp(const float* __restrict__ Xs, int* __restrict__ idx){
  int b = blockIdx.x; int t = threadIdx.x;
  __shared__ float Xh[32*388];
  __shared__ float snl[32];
  __shared__ float D[32*33];
  for (int k=t;k<32*384;k+=256){ int n=k/384, c=k-n*384; Xh[n*388+c] = Xs[(size_t)b*32*384 + k]; }
  __syncthreads();
  if (t<32){ double s=0.0; for (int c=0;c<384;c++){ double v=(double)Xh[t*388+c]; s+=v*v; } snl[t]=(float)s; }
  __syncthreads();
  for (int p=t;p<1024;p+=256){
    int n=p>>5, m=p&31;
    const float* A=&Xh[n*388]; const float* B=&Xh[m*388];
    double s=0.0;
    for (int c=0;c<384;c++) s += (double)A[c]*(double)B[c];
    D[n*33+m] = (float)((double)snl[m] - 2.0*s);
  }
  __syncthreads();
  if (t<32){
    float v0=3.4e38f,v1=3.4e38f; int i0=0,i1=0;
    for (int m=0;m<32;m++){
      float v=D[t*33+m];
      if (v < v0){ v1=v0;i1=i0; v0=v;i0=m; }
      else if (v < v1){ v1=v;i1=m; }
    }
    idx[((size_t)b*32+t)*2]=i0; idx[((size_t)b*32+t)*2+1]=i1;
  }
}

// ---------------- sparse GCN gather + stats + max/min ----------------
__global__ void k_gather_sp(const float* __restrict__ PQ, const int* __restrict__ idx,
                            float* __restrict__ umax, float* __restrict__ umin, double* __restrict__ part){
  int b = blockIdx.x; int t = threadIdx.x; // 512
  double s=0.0, s2=0.0;
  for (int n=0;n<32;n++){
    float qv = PQ[((size_t)b*32+n)*1024 + 512 + t];
    float mxv=-3.4e38f, mnv=3.4e38f;
    #pragma unroll
    for (int k=0;k<2;k++){
      int m = idx[((size_t)b*32+n)*2+k] & 31;
      float h = PQ[((size_t)b*32+m)*1024 + t] + qv;
      mxv=fmaxf(mxv,h); mnv=fminf(mnv,h); s+=h; s2+=(double)h*(double)h;
    }
    umax[((size_t)b*32+n)*512+t]=mxv; umin[((size_t)b*32+n)*512+t]=mnv;
  }
  part[((size_t)b*512+t)*2]=s; part[((size_t)b*512+t)*2+1]=s2;
}

// ---------------- FPS (16 of 32) ----------------
__global__ void k_fps(const float* __restrict__ coor, int* __restrict__ fps){
  int b = blockIdx.x; int t = threadIdx.x; // 64
  __shared__ float C[32*64]; __shared__ float dist[32]; __shared__ int fs;
  for (int k=t;k<2048;k+=64) C[k] = coor[(size_t)b*2048 + k];
  if (t<32) dist[t]=1e10f;
  if (t==0) fs=0;
  __syncthreads();
  for (int it=0; it<16; it++){
    int f = fs;
    if (t==0) fps[b*16+it] = f;
    if (t<32){
      float d=0.f;
      for (int c=0;c<64;c++){ float df = C[t*64+c]-C[f*64+c]; d += df*df; }
      dist[t] = fminf(dist[t], d);
    }
    __syncthreads();
    if (t==0){
      float bd=-1.f; int bi=0;
      for (int n=0;n<32;n++){ if (dist[n]>bd){bd=dist[n];bi=n;} }
      fs=bi;
    }
    __syncthreads();
  }
}

// ---------------- outputs 0 and 2 ----------------
__global__ void k_out0(const float* __restrict__ usp, const int* __restrict__ fps, float* __restrict__ out0){
  int b = blockIdx.y, s = blockIdx.x; int t = threadIdx.x; // 512
  int n = fps[b*16+s] & 31;
  out0[((size_t)b*512 + t)*16 + s] = usp[((size_t)b*32+n)*512 + t];
}
__global__ void k_out2(const float* __restrict__ coor, const int* __restrict__ fps, float* __restrict__ out2){
  int b = blockIdx.x; int t = threadIdx.x; // 256
  for (int e=t; e<1024; e+=256){
    int s=e>>6, c=e&63;
    out2[(size_t)b*1024 + e] = coor[((size_t)b*32 + (fps[b*16+s]&31))*64 + c];
  }
}

// ---------------- dcv conv (1x3, stride 2, pad 1): q-split, grid (16,4,8) ----------------
__global__ __launch_bounds__(256) void k_dcv(const float* __restrict__ gdn, const int* __restrict__ fps,
                      const float* __restrict__ w, const float* __restrict__ bias,
                      float* __restrict__ pre, double* __restrict__ part){
  int s = blockIdx.x, qg = blockIdx.y, b = blockIdx.z; int t = threadIdx.x; // 256 = oc
  __shared__ float I[17*256];  // 17.4 KB: rows p = 16*qg-1 .. 16*qg+15
  int n0 = (fps[b*16+s] & 31)*64;
  const size_t gbase = ((size_t)b*NPTS + n0)*256;
  for (int e=t; e<17*256; e+=256){
    int lp = e>>8, c = e&255;
    int p = 16*qg - 1 + lp;
    I[e] = (p >= 0) ? gdn[gbase + (size_t)p*256 + c] : 0.f;
  }
  __syncthreads();
  float acc[8];
  float bv = bias[t];
  #pragma unroll
  for (int q=0;q<8;q++) acc[q]=bv;
  for (int ci=0; ci<256; ci+=4){
    float wv[4][3];
    const float* wp = w + ((size_t)t*256 + ci)*3;
    #pragma unroll
    for (int u=0;u<4;u++){ wv[u][0]=wp[u*3]; wv[u][1]=wp[u*3+1]; wv[u][2]=wp[u*3+2]; }
    #pragma unroll
    for (int q=0;q<8;q++){
      float4 a0 = *(const float4*)&I[(2*q  )*256 + ci];
      float4 a1 = *(const float4*)&I[(2*q+1)*256 + ci];
      float4 a2 = *(const float4*)&I[(2*q+2)*256 + ci];
      acc[q] += a0.x*wv[0][0] + a0.y*wv[1][0] + a0.z*wv[2][0] + a0.w*wv[3][0];
      acc[q] += a1.x*wv[0][1] + a1.y*wv[1][1] + a1.z*wv[2][1] + a1.w*wv[3][1];
      acc[q] += a2.x*wv[0][2] + a2.y*wv[1][2] + a2.z*wv[2][2] + a2.w*wv[3][2];
    }
  }
  double ss=0.0, ss2=0.0;
  #pragma unroll
  for (int q=0;q<8;q++){ ss += acc[q]; ss2 += (double)acc[q]*(double)acc[q]; }
  float* o = pre + (((size_t)b*256 + t)*16 + s)*32 + qg*8;
  #pragma unroll
  for (int q=0;q<8;q++) o[q] = acc[q];
  size_t blk = ((size_t)b*16 + s)*4 + qg;
  part[(blk*256 + t)*2] = ss; part[(blk*256 + t)*2+1] = ss2;
}

__global__ void k_epi_dcv(const float* __restrict__ pre, const float* __restrict__ mv,
                          const float* __restrict__ g, const float* __restrict__ be,
                          float* __restrict__ out1){
  size_t i = (size_t)blockIdx.x*256 + threadIdx.x; // 1,048,576
  int c = (int)((i>>9) & 255);
  float gg = g[c];
  float y = gg*(pre[i]-mv[c*2])*mv[c*2+1] + be[c];
  out1[i] = lrelu(y);
}

extern "C" void kernel_launch(void* const* d_in, const int* in_sizes, int n_in,
                              void* d_out, int out_size, void* d_ws, size_t ws_size,
                              hipStream_t stream){
  const float* sparse = (const float*)d_in[0];
  const float* dense  = (const float*)d_in[1];
  const float* coor   = (const float*)d_in[2];
  const float* d2s_w  = (const float*)d_in[3];
  const float* d2s_b  = (const float*)d_in[4];
  const float* d2s_g  = (const float*)d_in[5];
  const float* d2s_be = (const float*)d_in[6];
  const float* gsp_w  = (const float*)d_in[7];
  const float* gsp_b  = (const float*)d_in[8];
  const float* gsp_g  = (const float*)d_in[9];
  const float* gsp_be = (const float*)d_in[10];
  const float* gdn_w  = (const float*)d_in[11];
  const float* gdn_b  = (const float*)d_in[12];
  const float* gdn_g  = (const float*)d_in[13];
  const float* gdn_be = (const float*)d_in[14];
  const float* dcv_w  = (const float*)d_in[15];
  const float* dcv_b  = (const float*)d_in[16];
  const float* dcv_g  = (const float*)d_in[17];
  const float* dcv_be = (const float*)d_in[18];

  float* out0 = (float*)d_out;
  float* out1 = out0 + 8*512*16;
  float* out2 = out1 + (size_t)8*256*512;

  char* base = (char*)d_ws; size_t off = 0;
  auto alloc = [&](size_t bytes)->void*{ void* p = base + off; off += (bytes + 255) & ~(size_t)255; return p; };
  float* Xdn  = (float*)alloc((size_t)8*2048*384*4);
  float* sn   = (float*)alloc((size_t)8*2048*4);
  int*   idxd = (int*)alloc((size_t)8*2048*10*4);
  float* PQ   = (float*)alloc((size_t)8*2048*512*4);
  float* dmax = (float*)alloc((size_t)8*2048*256*4);
  float* dmin = (float*)alloc((size_t)8*2048*256*4);
  double* partdn = (double*)alloc((size_t)256*256*2*8);
  float* mvdn = (float*)alloc(256*2*4);
  float* Wcd  = (float*)alloc((size_t)512*384*4);
  float* Wcs  = (float*)alloc((size_t)1024*384*4);
  float* Xs   = (float*)alloc((size_t)8*32*384*4);
  int*   idxs = (int*)alloc(8*32*2*4);
  float* PQs  = (float*)alloc((size_t)8*32*1024*4);
  float* umax = (float*)alloc((size_t)8*32*512*4);
  float* umin = (float*)alloc((size_t)8*32*512*4);
  double* partsp = (double*)alloc((size_t)8*512*2*8);
  float* mvsp = (float*)alloc(512*2*4);
  float* d2mx = (float*)alloc((size_t)8*32*128*4);
  float* d2mn = (float*)alloc((size_t)8*32*128*4);
  double* partd2 = (double*)alloc((size_t)256*128*2*8);
  float* mvd2 = (float*)alloc(128*2*4);
  int* fps = (int*)alloc(8*16*4);
  float* dcvpre = (float*)alloc((size_t)8*256*512*4);
  double* partdcv = (double*)alloc((size_t)512*256*2*8);
  float* mvdcv = (float*)alloc(256*2*4);
  if (off > ws_size) return;  // diagnostic: output stays zero -> ws too small

  // Dot (4 batches x 2048 x 2048 f32 = 67.1 MB) overlays PQ..mvdcv (~73 MB):
  // everything in that region is written only AFTER k_sel consumed Dot.
  float* Dot = PQ;

  k_build_xdn<<<dim3(32,8), 256, 0, stream>>>(dense, sparse, Xdn);
  k_sn<<<64, 256, 0, stream>>>(Xdn, sn);
  k_dist_tri<<<dim3(136,1,4), 256, 0, stream>>>(Xdn, Dot, 0);
  k_sel<<<2048, 256, 0, stream>>>(Dot, sn, idxd, 0);
  k_dist_tri<<<dim3(136,1,4), 256, 0, stream>>>(Xdn, Dot, 4);
  k_sel<<<2048, 256, 0, stream>>>(Dot, sn, idxd, 4);
  k_prepw<<<768, 256, 0, stream>>>(gdn_w, Wcd, 256);
  k_prepw<<<1536, 256, 0, stream>>>(gsp_w, Wcs, 512);
  k_gemm_pq2<<<dim3(4,16,8), 256, 0, stream>>>(Xdn, Wcd, gdn_b, PQ);
  k_gather_dn<<<dim3(32,8), 256, 0, stream>>>(PQ, idxd, dmax, dmin, partdn);
  k_reduce<<<256, 64, 0, stream>>>(partdn, mvdn, 256, 256, 163840);
  k_epi<<<16384, 256, 0, stream>>>(dmin, dmax, mvdn, gdn_g, gdn_be, 256, (size_t)8*2048*256);
  k_d2s<<<dim3(32,8), 128, 0, stream>>>(dense, d2s_w, d2s_b, d2mx, d2mn, partd2);
  k_reduce<<<128, 64, 0, stream>>>(partd2, mvd2, 256, 128, 15872);
  k_build_xs<<<8, 384, 0, stream>>>(sparse, d2mx, d2mn, mvd2, d2s_g, d2s_be, Xs);
  k_knn_sp<<<8, 256, 0, stream>>>(Xs, idxs);
  k_gemm_pq<<<dim3(16,1,8), 256, 0, stream>>>(Xs, Wcs, gsp_b, PQs, 32, 1024, 512);
  k_gather_sp<<<8, 512, 0, stream>>>(PQs, idxs, umax, umin, partsp);
  k_reduce<<<512, 64, 0, stream>>>(partsp, mvsp, 8, 512, 512);
  k_epi<<<512, 256, 0, stream>>>(umin, umax, mvsp, gsp_g, gsp_be, 512, (size_t)8*32*512);
  k_fps<<<8, 64, 0, stream>>>(coor, fps);
  k_out0<<<dim3(16,8), 512, 0, stream>>>(umax, fps, out0);
  k_out2<<<8, 256, 0, stream>>>(coor, fps, out2);
  k_dcv<<<dim3(16,4,8), 256, 0, stream>>>(dmax, fps, dcv_w, dcv_b, dcvpre, partdcv);
  k_reduce<<<256, 64, 0, stream>>>(partdcv, mvdcv, 512, 256, 4096);
  k_epi_dcv<<<4096, 256, 0, stream>>>(dcvpre, mvdcv, dcv_g, dcv_be, out1);
}

// Round 17
// 695.270 us; speedup vs baseline: 2.2537x; 1.0933x over previous
//
#include <hip/hip_runtime.h>

#define NPTS 2048
#define CUF 384

__device__ __forceinline__ float lrelu(float y){ return y>=0.f ? y : 0.2f*y; }

// async global->LDS, 16B per lane; LDS dest = wave-uniform base + lane*16
#define GLD16(g, l) __builtin_amdgcn_global_load_lds( \
    (const __attribute__((address_space(1))) void*)(g), \
    (__attribute__((address_space(3))) void*)(l), 16, 0, 0)

// ---------------- build X_dn (point-major f32 [8][2048][384]) ----------------
__global__ void k_build_xdn(const float* __restrict__ dense,
                            const float* __restrict__ sparse,
                            float* __restrict__ X){
  int b = blockIdx.y, ch = blockIdx.x;  // ch = stick 0..31 (64 points)
  int t = threadIdx.x;                  // 256
  __shared__ float tile[64*128];        // 32 KB
  for (int k=0;k<32;k++){
    int f = t + k*256;                  // f = c*64 + j, c<128
    int c = f>>6, j = f&63;
    tile[j*128 + c] = dense[((size_t)b*128 + c)*NPTS + ch*64 + j];
  }
  __syncthreads();
  for (int k=0;k<32;k++){
    int f = t + k*256;                  // f = j*128 + c
    int j = f>>7, c = f&127;
    X[((size_t)b*NPTS + ch*64 + j)*CUF + c] = tile[f];
  }
  float v = sparse[((size_t)b*256 + t)*32 + ch];
  for (int j=0;j<64;j++) X[((size_t)b*NPTS + ch*64 + j)*CUF + 128 + t] = v;
}

// ---------------- row sum-of-squares, numpy-pairwise mimic ----------------
__global__ void k_sn(const float* __restrict__ X, float* __restrict__ sn){
  int g = blockIdx.x*256 + threadIdx.x;   // 16384 = 8*2048 points
  if (g >= 8*NPTS) return;
  const float* row = X + (size_t)g*CUF;
  float blk[4];
  #pragma unroll
  for (int bI=0;bI<4;bI++){
    const float* p = row + bI*96;
    float r[8];
    #pragma unroll
    for (int l=0;l<8;l++) r[l] = __fmul_rn(p[l], p[l]);
    #pragma unroll 1
    for (int i=8;i<96;i+=8){
      #pragma unroll
      for (int l=0;l<8;l++) r[l] = __fadd_rn(r[l], __fmul_rn(p[i+l], p[i+l]));
    }
    float s01 = __fadd_rn(r[0], r[1]);
    float s23 = __fadd_rn(r[2], r[3]);
    float s45 = __fadd_rn(r[4], r[5]);
    float s67 = __fadd_rn(r[6], r[7]);
    blk[bI] = __fadd_rn(__fadd_rn(s01, s23), __fadd_rn(s45, s67));
  }
  sn[g] = __fadd_rn(__fadd_rn(blk[0], blk[1]), __fadd_rn(blk[2], blk[3]));
}

// ---------------- triangular dot tiles -> global Dot[bb][r][c] ----------------
__global__ __launch_bounds__(256) void k_dist_tri(
    const float* __restrict__ X, float* __restrict__ Dot, int b_base){
  int z = blockIdx.z; int b = b_base + z;
  int t = threadIdx.x;
  int tx = t & 15, ty = t >> 4;
  int idx = blockIdx.x, rb = 0;
  while (idx >= 16 - rb){ idx -= 16 - rb; rb++; }
  int cb = rb + idx;
  __shared__ float U[8576];          // staging; Ds[128][67] aliases
  float* Xr = U;
  float* Xc = U + 4096;
  float* Ds = U;
  int r0 = rb*128;
  int c0 = cb*128;
  const size_t xb = (size_t)b*NPTS*CUF;
  const size_t zb = (size_t)z*NPTS*NPTS;

  int wv  = t >> 6;
  int sub = (t & 63) >> 3;
  int gs  = t & 7;
  int rowsA[4]; int swzA[4];
  #pragma unroll
  for (int cc=0;cc<4;cc++){
    int grp = wv*4 + cc;
    int row = grp*8 + sub;
    rowsA[cc] = row;
    swzA[cc] = 4*(gs ^ (row&7));
  }

  float acc[8][8];
  #pragma unroll
  for (int i=0;i<8;i++){
    #pragma unroll
    for (int j=0;j<8;j++) acc[i][j] = 0.f;
  }
  for (int kt=0; kt<12; kt++){
    int k0 = kt*32;
    __syncthreads();
    #pragma unroll
    for (int cc=0;cc<4;cc++){
      int grp = wv*4 + cc;
      GLD16(X + xb + (size_t)(r0+rowsA[cc])*CUF + k0 + swzA[cc], Xr + grp*256);
      GLD16(X + xb + (size_t)(c0+rowsA[cc])*CUF + k0 + swzA[cc], Xc + grp*256);
    }
    __syncthreads();
    #pragma unroll
    for (int kk=0; kk<32; kk+=4){
      int G = kk>>2;
      float4 aa[8], bb[8];
      #pragma unroll
      for (int i=0;i<8;i++){ int r = ty+16*i; aa[i] = *(const float4*)&Xr[r*32 + 4*(G ^ (r&7))]; }
      #pragma unroll
      for (int j=0;j<8;j++){ int r = tx+16*j; bb[j] = *(const float4*)&Xc[r*32 + 4*(G ^ (r&7))]; }
      #pragma unroll
      for (int i=0;i<8;i++){
        #pragma unroll
        for (int j=0;j<8;j++){
          float a_ = acc[i][j];
          a_ = fmaf(aa[i].x, bb[j].x, a_);
          a_ = fmaf(aa[i].y, bb[j].y, a_);
          a_ = fmaf(aa[i].z, bb[j].z, a_);
          a_ = fmaf(aa[i].w, bb[j].w, a_);
          acc[i][j] = a_;
        }
      }
    }
  }
  // row region
  #pragma unroll
  for (int i=0;i<8;i++){
    size_t rbase = zb + (size_t)(r0 + ty + 16*i)*NPTS + c0;
    #pragma unroll
    for (int j=0;j<8;j++) Dot[rbase + tx + 16*j] = acc[i][j];
  }
  // transposed region (off-diagonal)
  if (rb != cb){
    for (int h=0; h<2; h++){
      __syncthreads();
      #pragma unroll
      for (int i2=0;i2<4;i2++){
        #pragma unroll
        for (int j=0;j<8;j++){
          Ds[(tx+16*j)*67 + ty + 16*i2] = acc[h*4+i2][j];
        }
      }
      __syncthreads();
      for (int e=t; e<128*64; e+=256){
        int col = e>>6, rr = e&63;
        Dot[zb + (size_t)(c0+col)*NPTS + r0 + h*64 + rr] = Ds[col*67 + rr];
      }
    }
  }
}

// ---------------- whole-row top-10: one wave per row, u64-key wave-min ----------------
__global__ __launch_bounds__(256) void k_sel(const float* __restrict__ Dot,
                                             const float* __restrict__ sn,
                                             int* __restrict__ idx, int b_base){
  int t = threadIdx.x;
  int lane = t & 63, w = t >> 6;
  int rglob = blockIdx.x*4 + w;
  int bb = rglob >> 11;
  int r  = rglob & 2047;
  int b  = b_base + bb;
  const float* drow = Dot + ((size_t)bb*NPTS + r)*NPTS;
  const float* snp  = sn + (size_t)b*NPTS;
  float snr = snp[r];
  unsigned long long key[32];
  #pragma unroll
  for (int k=0;k<8;k++){
    int cbase = k*256 + lane*4;          // coalesced: wave covers contiguous 1KB
    float4 dd = *(const float4*)&drow[cbase];
    float4 ss = *(const float4*)&snp[cbase];
    float v0 = __fsub_rn(__fadd_rn(snr, ss.x), __fmul_rn(2.0f, dd.x));
    float v1 = __fsub_rn(__fadd_rn(snr, ss.y), __fmul_rn(2.0f, dd.y));
    float v2 = __fsub_rn(__fadd_rn(snr, ss.z), __fmul_rn(2.0f, dd.z));
    float v3 = __fsub_rn(__fadd_rn(snr, ss.w), __fmul_rn(2.0f, dd.w));
    float vv[4] = {v0, v1, v2, v3};
    #pragma unroll
    for (int u=0;u<4;u++){
      unsigned int bits = __float_as_uint(vv[u]);
      unsigned int flip = bits ^ ((unsigned int)((int)bits >> 31) | 0x80000000u);
      key[k*4+u] = ((unsigned long long)flip << 32) | (unsigned int)(cbase + u);
    }
  }
  unsigned long long last = 0ull;
  int out[10];
  #pragma unroll
  for (int q=0;q<10;q++){
    const unsigned long long INF = 0xFFFFFFFFFFFFFFFFull;
    unsigned long long m0[16];
    #pragma unroll
    for (int s=0;s<16;s++){
      unsigned long long a = (key[s]    > last) ? key[s]    : INF;
      unsigned long long c = (key[s+16] > last) ? key[s+16] : INF;
      m0[s] = (c < a) ? c : a;
    }
    #pragma unroll
    for (int s=0;s<8;s++) m0[s] = (m0[s+8] < m0[s]) ? m0[s+8] : m0[s];
    #pragma unroll
    for (int s=0;s<4;s++) m0[s] = (m0[s+4] < m0[s]) ? m0[s+4] : m0[s];
    m0[0] = (m0[2] < m0[0]) ? m0[2] : m0[0];
    m0[1] = (m0[3] < m0[1]) ? m0[3] : m0[1];
    unsigned long long m = (m0[1] < m0[0]) ? m0[1] : m0[0];
    #pragma unroll
    for (int sh=1; sh<64; sh<<=1){
      unsigned long long o = (unsigned long long)__shfl_xor((long long)m, sh, 64);
      m = (o < m) ? o : m;
    }
    last = m;
    out[q] = (int)(m & 0xFFFFFFFFull);
  }
  if (lane == 0){
    int* o = idx + ((size_t)b*NPTS + r)*10;
    #pragma unroll
    for (int q=0;q<10;q++) o[q] = out[q];
  }
}

// ---------------- W -> [W1 ; W2-W1], both weight matrices in one launch ----------------
__global__ void k_prepw2(const float* __restrict__ gdn_w, const float* __restrict__ gsp_w,
                         float* __restrict__ Wcd, float* __restrict__ Wcs){
  int g = blockIdx.x*256 + threadIdx.x;
  if (g < 512*CUF){
    int o = g / CUF, c = g % CUF;
    float v;
    if (o < 256) v = gdn_w[(size_t)o*768 + c];
    else { int oo = o - 256; v = gdn_w[(size_t)oo*768 + 384 + c] - gdn_w[(size_t)oo*768 + c]; }
    Wcd[g] = v;
  } else {
    int g2 = g - 512*CUF;
    if (g2 < 1024*CUF){
      int o = g2 / CUF, c = g2 % CUF;
      float v;
      if (o < 512) v = gsp_w[(size_t)o*768 + c];
      else { int oo = o - 512; v = gsp_w[(size_t)oo*768 + 384 + c] - gsp_w[(size_t)oo*768 + c]; }
      Wcs[g2] = v;
    }
  }
}

// ---------------- dense GEMM 128x128x(BK=32), gload_lds staging ----------------
__global__ __launch_bounds__(256) void k_gemm_pq2(const float* __restrict__ A, const float* __restrict__ W,
                         const float* __restrict__ bias, float* __restrict__ OUT){
  int b = blockIdx.z, mb = blockIdx.y, ob = blockIdx.x;   // (4,16,8)
  int t = threadIdx.x; int tx = t&15, ty = t>>4;
  __shared__ float Xa[4096];
  __shared__ float Xw[4096];
  int m0 = mb*128, o0 = ob*128;
  float acc[8][8];
  #pragma unroll
  for (int i=0;i<8;i++){
    #pragma unroll
    for (int j=0;j<8;j++) acc[i][j] = 0.f;
  }
  int wv  = t >> 6;
  int sub = (t & 63) >> 3;
  int gs  = t & 7;
  int rowsA[4]; int swzA[4];
  #pragma unroll
  for (int cc=0;cc<4;cc++){
    int grp = wv*4 + cc;
    int row = grp*8 + sub;
    rowsA[cc] = row;
    swzA[cc] = 4*(gs ^ (row&7));
  }
  for (int kt=0; kt<12; kt++){
    int k0 = kt*32;
    __syncthreads();
    #pragma unroll
    for (int cc=0;cc<4;cc++){
      int grp = wv*4 + cc;
      GLD16(A + ((size_t)b*NPTS + m0 + rowsA[cc])*CUF + k0 + swzA[cc], Xa + grp*256);
      GLD16(W + (size_t)(o0 + rowsA[cc])*CUF + k0 + swzA[cc], Xw + grp*256);
    }
    __syncthreads();
    #pragma unroll
    for (int kk=0; kk<32; kk+=4){
      int G = kk>>2;
      float4 aa[8], bb[8];
      #pragma unroll
      for (int i=0;i<8;i++){ int r = ty+16*i; aa[i] = *(const float4*)&Xa[r*32 + 4*(G ^ (r&7))]; }
      #pragma unroll
      for (int j=0;j<8;j++){ int r = tx+16*j; bb[j] = *(const float4*)&Xw[r*32 + 4*(G ^ (r&7))]; }
      #pragma unroll
      for (int i=0;i<8;i++){
        #pragma unroll
        for (int j=0;j<8;j++){
          float a_ = acc[i][j];
          a_ = fmaf(aa[i].x, bb[j].x, a_);
          a_ = fmaf(aa[i].y, bb[j].y, a_);
          a_ = fmaf(aa[i].z, bb[j].z, a_);
          a_ = fmaf(aa[i].w, bb[j].w, a_);
          acc[i][j] = a_;
        }
      }
    }
  }
  #pragma unroll
  for (int i=0;i<8;i++){
    int m = m0 + ty + 16*i;
    #pragma unroll
    for (int j=0;j<8;j++){
      int o = o0 + tx + 16*j;
      float v = acc[i][j];
      if (o >= 256) v += bias[o - 256];
      OUT[((size_t)b*NPTS + m)*512 + o] = v;
    }
  }
}

// ---------------- GEMM (small, for sparse path) ----------------
__global__ __launch_bounds__(256) void k_gemm_pq(const float* __restrict__ A, const float* __restrict__ W,
                         const float* __restrict__ bias,
                         float* __restrict__ OUT, int M, int Ototal, int Ohalf){
  int b = blockIdx.z, mb = blockIdx.y, ob = blockIdx.x;
  int t = threadIdx.x; int tr = t&15, tc = t>>4;
  __shared__ float At[64][68], Wt[64][68];
  int m0 = mb*64, o0 = ob*64;
  float acc[4][4];
  #pragma unroll
  for(int i=0;i<4;i++){
    #pragma unroll
    for(int j=0;j<4;j++) acc[i][j]=0.f;
  }
  int li = t>>2, lk = (t&3)*16;
  for (int kt=0;kt<6;kt++){
    int k0 = kt*64;
    {
      int m = m0 + li;
      if (m < M){
        const float4* p = (const float4*)(A + ((size_t)b*M + m)*CUF + k0 + lk);
        #pragma unroll
        for (int e=0;e<4;e++) *(float4*)&At[li][lk+e*4] = p[e];
      } else {
        float4 z = make_float4(0.f,0.f,0.f,0.f);
        #pragma unroll
        for (int e=0;e<4;e++) *(float4*)&At[li][lk+e*4] = z;
      }
      const float4* pw = (const float4*)(W + (size_t)(o0+li)*CUF + k0 + lk);
      #pragma unroll
      for (int e=0;e<4;e++) *(float4*)&Wt[li][lk+e*4] = pw[e];
    }
    __syncthreads();
    #pragma unroll
    for (int k4=0;k4<16;k4++){
      float4 aa[4], bb[4];
      aa[0] = *(const float4*)&At[tr   ][k4*4];
      aa[1] = *(const float4*)&At[tr+16][k4*4];
      aa[2] = *(const float4*)&At[tr+32][k4*4];
      aa[3] = *(const float4*)&At[tr+48][k4*4];
      bb[0] = *(const float4*)&Wt[tc   ][k4*4];
      bb[1] = *(const float4*)&Wt[tc+16][k4*4];
      bb[2] = *(const float4*)&Wt[tc+32][k4*4];
      bb[3] = *(const float4*)&Wt[tc+48][k4*4];
      #pragma unroll
      for(int i=0;i<4;i++){
        #pragma unroll
        for(int j=0;j<4;j++)
          acc[i][j] += aa[i].x*bb[j].x + aa[i].y*bb[j].y + aa[i].z*bb[j].z + aa[i].w*bb[j].w;
      }
    }
    __syncthreads();
  }
  #pragma unroll
  for(int i=0;i<4;i++){
    int m = m0 + tr + 16*i;
    if (m < M){
      #pragma unroll
      for(int j=0;j<4;j++){
        int o = o0 + tc + 16*j;
        float v = acc[i][j];
        if (o >= Ohalf) v += bias[o - Ohalf];
        OUT[((size_t)b*M + m)*Ototal + o] = v;
      }
    }
  }
}

// ---------------- dense GCN gather + stats + max/min ----------------
__global__ __launch_bounds__(256) void k_gather_dn(const float* __restrict__ PQ, const int* __restrict__ idx,
                            float* __restrict__ dmax, float* __restrict__ dmin, double* __restrict__ part){
  int b = blockIdx.y, nb = blockIdx.x; int t = threadIdx.x;
  __shared__ int sidx[640];
  int n0 = nb*64;
  for (int k=t; k<640; k+=256) sidx[k] = idx[((size_t)b*NPTS + n0)*10 + k] & 2047;
  __syncthreads();
  double s=0.0, s2=0.0;
  const size_t pb = (size_t)b*NPTS*512;
  for (int n=0;n<64;n++){
    float qv = PQ[pb + (size_t)(n0+n)*512 + 256 + t];
    float mx = -3.4e38f, mn = 3.4e38f;
    #pragma unroll
    for (int k=0;k<10;k++){
      int m = sidx[n*10+k];
      float h = PQ[pb + (size_t)m*512 + t] + qv;
      mx = fmaxf(mx,h); mn = fminf(mn,h);
      s += h; s2 += (double)h*(double)h;
    }
    dmax[((size_t)b*NPTS + n0+n)*256 + t] = mx;
    dmin[((size_t)b*NPTS + n0+n)*256 + t] = mn;
  }
  size_t blk = (size_t)b*32 + nb;
  part[(blk*256 + t)*2] = s; part[(blk*256 + t)*2+1] = s2;
}

// ---------------- generic channel stats reduce -> (mean, invstd) ----------------
__global__ void k_reduce(const double* __restrict__ part, float* __restrict__ mv,
                         int nblk, int C, int count){
  int c = blockIdx.x; int t = threadIdx.x;
  double s=0.0, s2=0.0;
  for (int k=t;k<nblk;k+=64){ s += part[((size_t)k*C+c)*2]; s2 += part[((size_t)k*C+c)*2+1]; }
  #pragma unroll
  for (int off=32; off>=1; off>>=1){ s += __shfl_down(s, off, 64); s2 += __shfl_down(s2, off, 64); }
  if (t==0){
    double mean = s / (double)count;
    double var = s2 / (double)count - mean*mean;
    mv[c*2] = (float)mean;
    mv[c*2+1] = (float)(1.0 / sqrt(var + 1e-5));
  }
}

// ---------------- BN+act epilogue choosing max/min by sign(gamma); in-place on xmax ----------------
__global__ void k_epi(const float* __restrict__ xmin, float* __restrict__ xmax,
                      const float* __restrict__ mv, const float* __restrict__ g,
                      const float* __restrict__ be, int C, size_t total){
  size_t i = (size_t)blockIdx.x*256 + threadIdx.x;
  if (i>=total) return;
  int c = (int)(i % (size_t)C);
  float gg = g[c];
  float x = gg >= 0.f ? xmax[i] : xmin[i];
  float y = gg*(x - mv[c*2])*mv[c*2+1] + be[c];
  xmax[i] = lrelu(y);
}

// ---------------- d2s conv(1x3 valid) + stats + per-(b,c,s) max/min ----------------
__global__ __launch_bounds__(128) void k_d2s(const float* __restrict__ dense,
                      const float* __restrict__ w, const float* __restrict__ bias,
                      float* __restrict__ mx, float* __restrict__ mn, double* __restrict__ part){
  int b = blockIdx.y, s = blockIdx.x; int t = threadIdx.x; // 128
  __shared__ float IN[128*64];
  for (int k=0;k<64;k++){
    int f = t + k*128;
    int ci = f>>6, wj = f&63;
    IN[f] = dense[((size_t)b*128 + ci)*NPTS + s*64 + wj];
  }
  __syncthreads();
  float acc[62];
  float bv = bias[t];
  #pragma unroll
  for (int wj=0;wj<62;wj++) acc[wj]=bv;
  for (int ci=0;ci<128;ci++){
    const float* wp = w + ((size_t)t*128 + ci)*3;
    float w0 = wp[0], w1 = wp[1], w2 = wp[2];
    const float* row = &IN[ci*64];
    #pragma unroll
    for (int wj=0;wj<62;wj++) acc[wj] += row[wj]*w0 + row[wj+1]*w1 + row[wj+2]*w2;
  }
  float vmx=-3.4e38f, vmn=3.4e38f; double ss=0.0, ss2=0.0;
  #pragma unroll
  for (int wj=0;wj<62;wj++){ float v = acc[wj]; vmx=fmaxf(vmx,v); vmn=fminf(vmn,v); ss+=v; ss2+=(double)v*(double)v; }
  mx[((size_t)b*32+s)*128 + t] = vmx;
  mn[((size_t)b*32+s)*128 + t] = vmn;
  part[(((size_t)b*32+s)*128 + t)*2] = ss; part[(((size_t)b*32+s)*128 + t)*2+1] = ss2;
}

// ---------------- build union_sparse points Xs f32 [8][32][384] ----------------
__global__ void k_build_xs(const float* __restrict__ sparse,
                           const float* __restrict__ mx, const float* __restrict__ mn,
                           const float* __restrict__ mv, const float* __restrict__ g,
                           const float* __restrict__ be, float* __restrict__ Xs){
  int b = blockIdx.x; int c = threadIdx.x; // 384
  for (int n=0;n<32;n++){
    float v;
    if (c < 256) v = sparse[((size_t)b*256 + c)*32 + n];
    else {
      int cc = c-256;
      float gg = g[cc];
      float x = gg>=0.f ? mx[((size_t)b*32+n)*128+cc] : mn[((size_t)b*32+n)*128+cc];
      v = lrelu(gg*(x - mv[cc*2])*mv[cc*2+1] + be[cc]);
    }
    Xs[((size_t)b*32+n)*384 + c] = v;
  }
}

// ---------------- sparse kNN (k=2 of 32) ----------------
__global__ __launch_bounds__(256) void k_knn_sp(const float* __restrict__ Xs, int* __restrict__ idx){
  int b = blockIdx.x; int t = threadIdx.x;
  __shared__ float Xh[32*388];
  __shared__ float snl[32];
  __shared__ float D[32*33];
  for (int k=t;k<32*384;k+=256){ int n=k/384, c=k-n*384; Xh[n*388+c] = Xs[(size_t)b*32*384 + k]; }
  __syncthreads();
  if (t<32){ double s=0.0; for (int c=0;c<384;c++){ double v=(double)Xh[t*388+c]; s+=v*v; } snl[t]=(float)s; }
  __syncthreads();
  for (int p=t;p<1024;p+=256){
    int n=p>>5, m=p&31;
    const float* A=&Xh[n*388]; const float* B=&Xh[m*388];
    double s=0.0;
    for (int c=0;c<384;c++) s += (double)A[c]*(double)B[c];
    D[n*33+m] = (float)((double)snl[m] - 2.0*s);
  }
  __syncthreads();
  if (t<32){
    float v0=3.4e38f,v1=3.4e38f; int i0=0,i1=0;
    for (int m=0;m<32;m++){
      float v=D[t*33+m];
      if (v < v0){ v1=v0;i1=i0; v0=v;i0=m; }
      else if (v < v1){ v1=v;i1=m; }
    }
    idx[((size_t)b*32+t)*2]=i0; idx[((size_t)b*32+t)*2+1]=i1;
  }
}

// ---------------- sparse GCN gather + stats + max/min ----------------
__global__ void k_gather_sp(const float* __restrict__ PQ, const int* __restrict__ idx,
                            float* __restrict__ umax, float* __restrict__ umin, double* __restrict__ part){
  int b = blockIdx.x; int t = threadIdx.x; // 512
  double s=0.0, s2=0.0;
  for (int n=0;n<32;n++){
    float qv = PQ[((size_t)b*32+n)*1024 + 512 + t];
    float mxv=-3.4e38f, mnv=3.4e38f;
    #pragma unroll
    for (int k=0;k<2;k++){
      int m = idx[((size_t)b*32+n)*2+k] & 31;
      float h = PQ[((size_t)b*32+m)*1024 + t] + qv;
      mxv=fmaxf(mxv,h); mnv=fminf(mnv,h); s+=h; s2+=(double)h*(double)h;
    }
    umax[((size_t)b*32+n)*512+t]=mxv; umin[((size_t)b*32+n)*512+t]=mnv;
  }
  part[((size_t)b*512+t)*2]=s; part[((size_t)b*512+t)*2+1]=s2;
}

// ---------------- FPS (16 of 32) ----------------
__global__ void k_fps(const float* __restrict__ coor, int* __restrict__ fps){
  int b = blockIdx.x; int t = threadIdx.x; // 64
  __shared__ float C[32*64]; __shared__ float dist[32]; __shared__ int fs;
  for (int k=t;k<2048;k+=64) C[k] = coor[(size_t)b*2048 + k];
  if (t<32) dist[t]=1e10f;
  if (t==0) fs=0;
  __syncthreads();
  for (int it=0; it<16; it++){
    int f = fs;
    if (t==0) fps[b*16+it] = f;
    if (t<32){
      float d=0.f;
      for (int c=0;c<64;c++){ float df = C[t*64+c]-C[f*64+c]; d += df*df; }
      dist[t] = fminf(dist[t], d);
    }
    __syncthreads();
    if (t==0){
      float bd=-1.f; int bi=0;
      for (int n=0;n<32;n++){ if (dist[n]>bd){bd=dist[n];bi=n;} }
      fs=bi;
    }
    __syncthreads();
  }
}

// ---------------- outputs 0 and 2 fused ----------------
__global__ void k_outs(const float* __restrict__ usp, const float* __restrict__ coor,
                       const int* __restrict__ fps, float* __restrict__ out0, float* __restrict__ out2){
  int g = blockIdx.x*256 + threadIdx.x;  // 65536 + 8192 = 73728
  if (g < 65536){
    int b = g >> 13; int rem = g & 8191; int t = rem >> 4; int s = rem & 15;
    int n = fps[b*16+s] & 31;
    out0[((size_t)b*512 + t)*16 + s] = usp[((size_t)b*32+n)*512 + t];
  } else {
    int e = g - 65536;
    if (e < 8192){
      int b = e >> 10; int r = e & 1023; int s = r>>6, c = r&63;
      out2[(size_t)b*1024 + r] = coor[((size_t)b*32 + (fps[b*16+s]&31))*64 + c];
    }
  }
}

// ---------------- dcv conv (1x3, stride 2, pad 1): q-split, grid (16,4,8) ----------------
__global__ __launch_bounds__(256) void k_dcv(const float* __restrict__ gdn, const int* __restrict__ fps,
                      const float* __restrict__ w, const float* __restrict__ bias,
                      float* __restrict__ pre, double* __restrict__ part){
  int s = blockIdx.x, qg = blockIdx.y, b = blockIdx.z; int t = threadIdx.x; // 256 = oc
  __shared__ float I[17*256];
  int n0 = (fps[b*16+s] & 31)*64;
  const size_t gbase = ((size_t)b*NPTS + n0)*256;
  for (int e=t; e<17*256; e+=256){
    int lp = e>>8, c = e&255;
    int p = 16*qg - 1 + lp;
    I[e] = (p >= 0) ? gdn[gbase + (size_t)p*256 + c] : 0.f;
  }
  __syncthreads();
  float acc[8];
  float bv = bias[t];
  #pragma unroll
  for (int q=0;q<8;q++) acc[q]=bv;
  for (int ci=0; ci<256; ci+=4){
    float wv[4][3];
    const float* wp = w + ((size_t)t*256 + ci)*3;
    #pragma unroll
    for (int u=0;u<4;u++){ wv[u][0]=wp[u*3]; wv[u][1]=wp[u*3+1]; wv[u][2]=wp[u*3+2]; }
    #pragma unroll
    for (int q=0;q<8;q++){
      float4 a0 = *(const float4*)&I[(2*q  )*256 + ci];
      float4 a1 = *(const float4*)&I[(2*q+1)*256 + ci];
      float4 a2 = *(const float4*)&I[(2*q+2)*256 + ci];
      acc[q] += a0.x*wv[0][0] + a0.y*wv[1][0] + a0.z*wv[2][0] + a0.w*wv[3][0];
      acc[q] += a1.x*wv[0][1] + a1.y*wv[1][1] + a1.z*wv[2][1] + a1.w*wv[3][1];
      acc[q] += a2.x*wv[0][2] + a2.y*wv[1][2] + a2.z*wv[2][2] + a2.w*wv[3][2];
    }
  }
  double ss=0.0, ss2=0.0;
  #pragma unroll
  for (int q=0;q<8;q++){ ss += acc[q]; ss2 += (double)acc[q]*(double)acc[q]; }
  float* o = pre + (((size_t)b*256 + t)*16 + s)*32 + qg*8;
  #pragma unroll
  for (int q=0;q<8;q++) o[q] = acc[q];
  size_t blk = ((size_t)b*16 + s)*4 + qg;
  part[(blk*256 + t)*2] = ss; part[(blk*256 + t)*2+1] = ss2;
}

__global__ void k_epi_dcv(const float* __restrict__ pre, const float* __restrict__ mv,
                          const float* __restrict__ g, const float* __restrict__ be,
                          float* __restrict__ out1){
  size_t i = (size_t)blockIdx.x*256 + threadIdx.x; // 1,048,576
  int c = (int)((i>>9) & 255);
  float gg = g[c];
  float y = gg*(pre[i]-mv[c*2])*mv[c*2+1] + be[c];
  out1[i] = lrelu(y);
}

extern "C" void kernel_launch(void* const* d_in, const int* in_sizes, int n_in,
                              void* d_out, int out_size, void* d_ws, size_t ws_size,
                              hipStream_t stream){
  const float* sparse = (const float*)d_in[0];
  const float* dense  = (const float*)d_in[1];
  const float* coor   = (const float*)d_in[2];
  const float* d2s_w  = (const float*)d_in[3];
  const float* d2s_b  = (const float*)d_in[4];
  const float* d2s_g  = (const float*)d_in[5];
  const float* d2s_be = (const float*)d_in[6];
  const float* gsp_w  = (const float*)d_in[7];
  const float* gsp_b  = (const float*)d_in[8];
  const float* gsp_g  = (const float*)d_in[9];
  const float* gsp_be = (const float*)d_in[10];
  const float* gdn_w  = (const float*)d_in[11];
  const float* gdn_b  = (const float*)d_in[12];
  const float* gdn_g  = (const float*)d_in[13];
  const float* gdn_be = (const float*)d_in[14];
  const float* dcv_w  = (const float*)d_in[15];
  const float* dcv_b  = (const float*)d_in[16];
  const float* dcv_g  = (const float*)d_in[17];
  const float* dcv_be = (const float*)d_in[18];

  float* out0 = (float*)d_out;
  float* out1 = out0 + 8*512*16;
  float* out2 = out1 + (size_t)8*256*512;

  char* base = (char*)d_ws; size_t off = 0;
  auto alloc = [&](size_t bytes)->void*{ void* p = base + off; off += (bytes + 255) & ~(size_t)255; return p; };
  float* Xdn  = (float*)alloc((size_t)8*2048*384*4);
  float* sn   = (float*)alloc((size_t)8*2048*4);
  int*   idxd = (int*)alloc((size_t)8*2048*10*4);
  float* PQ   = (float*)alloc((size_t)8*2048*512*4);
  float* dmax = (float*)alloc((size_t)8*2048*256*4);
  float* dmin = (float*)alloc((size_t)8*2048*256*4);
  double* partdn = (double*)alloc((size_t)256*256*2*8);
  float* mvdn = (float*)alloc(256*2*4);
  float* Wcd  = (float*)alloc((size_t)512*384*4);
  float* Wcs  = (float*)alloc((size_t)1024*384*4);
  float* Xs   = (float*)alloc((size_t)8*32*384*4);
  int*   idxs = (int*)alloc(8*32*2*4);
  float* PQs  = (float*)alloc((size_t)8*32*1024*4);
  float* umax = (float*)alloc((size_t)8*32*512*4);
  float* umin = (float*)alloc((size_t)8*32*512*4);
  double* partsp = (double*)alloc((size_t)8*512*2*8);
  float* mvsp = (float*)alloc(512*2*4);
  float* d2mx = (float*)alloc((size_t)8*32*128*4);
  float* d2mn = (float*)alloc((size_t)8*32*128*4);
  double* partd2 = (double*)alloc((size_t)256*128*2*8);
  float* mvd2 = (float*)alloc(128*2*4);
  int* fps = (int*)alloc(8*16*4);
  float* dcvpre = (float*)alloc((size_t)8*256*512*4);
  double* partdcv = (double*)alloc((size_t)512*256*2*8);
  float* mvdcv = (float*)alloc(256*2*4);
  if (off > ws_size) return;  // diagnostic: output stays zero -> ws too small

  // Big-Dot path: dedicated 134 MB buffer for all 8 batches if workspace allows;
  // otherwise the two-phase aliased path (Dot over PQ..mvdcv, 4 batches/round).
  size_t dotBytes = (size_t)8*NPTS*NPTS*4;
  float* Dot8 = (off + dotBytes <= ws_size) ? (float*)(base + off) : nullptr;
  float* Dot4 = PQ;

  k_build_xdn<<<dim3(32,8), 256, 0, stream>>>(dense, sparse, Xdn);
  k_sn<<<64, 256, 0, stream>>>(Xdn, sn);
  if (Dot8){
    k_dist_tri<<<dim3(136,1,8), 256, 0, stream>>>(Xdn, Dot8, 0);
    k_sel<<<4096, 256, 0, stream>>>(Dot8, sn, idxd, 0);
  } else {
    k_dist_tri<<<dim3(136,1,4), 256, 0, stream>>>(Xdn, Dot4, 0);
    k_sel<<<2048, 256, 0, stream>>>(Dot4, sn, idxd, 0);
    k_dist_tri<<<dim3(136,1,4), 256, 0, stream>>>(Xdn, Dot4, 4);
    k_sel<<<2048, 256, 0, stream>>>(Dot4, sn, idxd, 4);
  }
  k_prepw2<<<2304, 256, 0, stream>>>(gdn_w, gsp_w, Wcd, Wcs);
  k_gemm_pq2<<<dim3(4,16,8), 256, 0, stream>>>(Xdn, Wcd, gdn_b, PQ);
  k_gather_dn<<<dim3(32,8), 256, 0, stream>>>(PQ, idxd, dmax, dmin, partdn);
  k_reduce<<<256, 64, 0, stream>>>(partdn, mvdn, 256, 256, 163840);
  k_epi<<<16384, 256, 0, stream>>>(dmin, dmax, mvdn, gdn_g, gdn_be, 256, (size_t)8*2048*256);
  k_d2s<<<dim3(32,8), 128, 0, stream>>>(dense, d2s_w, d2s_b, d2mx, d2mn, partd2);
  k_reduce<<<128, 64, 0, stream>>>(partd2, mvd2, 256, 128, 15872);
  k_build_xs<<<8, 384, 0, stream>>>(sparse, d2mx, d2mn, mvd2, d2s_g, d2s_be, Xs);
  k_knn_sp<<<8, 256, 0, stream>>>(Xs, idxs);
  k_gemm_pq<<<dim3(16,1,8), 256, 0, stream>>>(Xs, Wcs, gsp_b, PQs, 32, 1024, 512);
  k_gather_sp<<<8, 512, 0, stream>>>(PQs, idxs, umax, umin, partsp);
  k_reduce<<<512, 64, 0, stream>>>(partsp, mvsp, 8, 512, 512);
  k_epi<<<512, 256, 0, stream>>>(umin, umax, mvsp, gsp_g, gsp_be, 512, (size_t)8*32*512);
  k_fps<<<8, 64, 0, stream>>>(coor, fps);
  k_outs<<<288, 256, 0, stream>>>(umax, coor, fps, out0, out2);
  k_dcv<<<dim3(16,4,8), 256, 0, stream>>>(dmax, fps, dcv_w, dcv_b, dcvpre, partdcv);
  k_reduce<<<256, 64, 0, stream>>>(partdcv, mvdcv, 512, 256, 4096);
  k_epi_dcv<<<4096, 256, 0, stream>>>(dcvpre, mvdcv, dcv_g, dcv_be, out1);
}